// Round 1
// baseline (1286.406 us; speedup 1.0000x reference)
//
#include <hip/hip_runtime.h>

#define N_NODES 50000
#define N_EDGES 300000
#define IN_DIM 128
#define HID 256
#define NHEADS 8
#define HDIM 32

// ---------------------------------------------------------------------------
// Generic tiled fp32 GEMM: C[M x N] = A[M x K] @ B[N x K]^T + rowscale[m]*bias[n]
// 64x64 tile, K-chunks of 64 staged transposed in LDS (padded stride 68).
// ---------------------------------------------------------------------------
constexpr int TILE = 64;
constexpr int KCHUNK = 64;
constexpr int LDT = 68; // padded float stride (16B-aligned, breaks bank alignment)

__global__ __launch_bounds__(256)
void gemm_bt_kernel(const float* __restrict__ A, const float* __restrict__ B,
                    const float* __restrict__ bias, const float* __restrict__ rowscale,
                    float* __restrict__ C, int M, int N, int K)
{
    __shared__ float As[KCHUNK * LDT];
    __shared__ float Bs[KCHUNK * LDT];
    const int t  = threadIdx.x;
    const int tx = t & 15;        // 0..15 -> n sub-tile
    const int ty = t >> 4;        // 0..15 -> m sub-tile
    const int m0 = blockIdx.y * TILE;
    const int n0 = blockIdx.x * TILE;

    float c[4][4] = {};

    const int r  = t >> 2;        // 0..63 row within tile (for staging)
    const int kb = (t & 3) * 16;  // 16 floats per thread per chunk

    for (int kc = 0; kc < K; kc += KCHUNK) {
        // stage A transposed: As[k][m]
        #pragma unroll
        for (int ii = 0; ii < 4; ++ii) {
            const int k = kb + ii * 4;
            float4 v = make_float4(0.f, 0.f, 0.f, 0.f);
            if (m0 + r < M)
                v = *reinterpret_cast<const float4*>(&A[(size_t)(m0 + r) * K + kc + k]);
            As[(k + 0) * LDT + r] = v.x;
            As[(k + 1) * LDT + r] = v.y;
            As[(k + 2) * LDT + r] = v.z;
            As[(k + 3) * LDT + r] = v.w;
        }
        // stage B transposed: Bs[k][n]  (N is a multiple of 64, no guard)
        #pragma unroll
        for (int ii = 0; ii < 4; ++ii) {
            const int k = kb + ii * 4;
            float4 v = *reinterpret_cast<const float4*>(&B[(size_t)(n0 + r) * K + kc + k]);
            Bs[(k + 0) * LDT + r] = v.x;
            Bs[(k + 1) * LDT + r] = v.y;
            Bs[(k + 2) * LDT + r] = v.z;
            Bs[(k + 3) * LDT + r] = v.w;
        }
        __syncthreads();

        #pragma unroll 4
        for (int k = 0; k < KCHUNK; ++k) {
            const float4 a4 = *reinterpret_cast<const float4*>(&As[k * LDT + ty * 4]);
            const float4 b4 = *reinterpret_cast<const float4*>(&Bs[k * LDT + tx * 4]);
            const float av[4] = {a4.x, a4.y, a4.z, a4.w};
            const float bv[4] = {b4.x, b4.y, b4.z, b4.w};
            #pragma unroll
            for (int i = 0; i < 4; ++i)
                #pragma unroll
                for (int j = 0; j < 4; ++j)
                    c[i][j] += av[i] * bv[j];
        }
        __syncthreads();
    }

    // store with bias
    #pragma unroll
    for (int i = 0; i < 4; ++i) {
        const int m = m0 + ty * 4 + i;
        if (m >= M) break;
        const float rs = rowscale ? rowscale[m] : 1.0f;
        #pragma unroll
        for (int j = 0; j < 4; ++j) {
            const int n = n0 + tx * 4 + j;
            C[(size_t)m * N + n] = c[i][j] + rs * bias[n];
        }
    }
}

// ---------------------------------------------------------------------------
// Edge attention: one wave (64 lanes) per edge.
// lane l: h = l>>3 (query head), g = l&7 (key head).
// scores[h][g] = dot32(Q[src][h], K[tgt][g]) / sqrt(32); softmax over g;
// msg float4 slot l (= elements 4l..4l+3) = sum_g attn[h][g]*V[tgt][g*32 + (l&7)*4 ..]
// + edge_emb[etype]; atomicAdd into acc[src], count[src] += 1.
// ---------------------------------------------------------------------------
__global__ __launch_bounds__(256)
void edge_attn_kernel(const int* __restrict__ edges, const int* __restrict__ etypes,
                      const float4* __restrict__ Q4, const float4* __restrict__ K4,
                      const float4* __restrict__ V4, const float4* __restrict__ EE4,
                      float* __restrict__ acc, float* __restrict__ countF)
{
    const int lane = threadIdx.x & 63;
    const int e = blockIdx.x * 4 + (threadIdx.x >> 6);
    if (e >= N_EDGES) return;

    const int src = edges[2 * e + 0];
    const int tgt = edges[2 * e + 1];
    const int h = lane >> 3;
    const int g = lane & 7;

    // ---- scores ----
    float4 q[8];
    #pragma unroll
    for (int d4 = 0; d4 < 8; ++d4)
        q[d4] = Q4[(size_t)src * 64 + h * 8 + d4];

    float s = 0.f;
    #pragma unroll
    for (int d4 = 0; d4 < 8; ++d4) {
        const float4 k4 = K4[(size_t)tgt * 64 + g * 8 + d4];
        s += q[d4].x * k4.x + q[d4].y * k4.y + q[d4].z * k4.z + q[d4].w * k4.w;
    }
    s *= 0.17677669529663687f; // 1/sqrt(32)

    // ---- softmax over g within 8-lane group ----
    float m = s;
    m = fmaxf(m, __shfl_xor(m, 1));
    m = fmaxf(m, __shfl_xor(m, 2));
    m = fmaxf(m, __shfl_xor(m, 4));
    const float p = __expf(s - m);
    float sum = p;
    sum += __shfl_xor(sum, 1);
    sum += __shfl_xor(sum, 2);
    sum += __shfl_xor(sum, 4);
    const float a = p / sum;

    // ---- msg: lane handles float4 slot `lane` (h = lane>>3, dd = lane&7) ----
    const int dd = lane & 7;
    float mx = 0.f, my = 0.f, mz = 0.f, mw = 0.f;
    #pragma unroll
    for (int gg = 0; gg < 8; ++gg) {
        const float ag = __shfl(a, (lane & 56) | gg);
        const float4 v4 = V4[(size_t)tgt * 64 + gg * 8 + dd];
        mx += ag * v4.x; my += ag * v4.y; mz += ag * v4.z; mw += ag * v4.w;
    }

    // ---- edge-type embedding ----
    const int et = etypes[e];
    const float4 e4 = EE4[(size_t)et * 64 + lane];
    mx += e4.x; my += e4.y; mz += e4.z; mw += e4.w;

    // ---- scatter ----
    float* dst = acc + (size_t)src * 256 + lane * 4;
    atomicAdd(dst + 0, mx);
    atomicAdd(dst + 1, my);
    atomicAdd(dst + 2, mz);
    atomicAdd(dst + 3, mw);
    if (lane == 0) atomicAdd(&countF[src], 1.0f);
}

// ---------------------------------------------------------------------------
extern "C" void kernel_launch(void* const* d_in, const int* in_sizes, int n_in,
                              void* d_out, int out_size, void* d_ws, size_t ws_size,
                              hipStream_t stream)
{
    const float* nf      = (const float*)d_in[0];
    const int*   edges   = (const int*)d_in[1];
    const int*   etypes  = (const int*)d_in[2];
    const float* Wq      = (const float*)d_in[3];
    const float* bq      = (const float*)d_in[4];
    const float* Wk      = (const float*)d_in[5];
    const float* bk      = (const float*)d_in[6];
    const float* Wv      = (const float*)d_in[7];
    const float* bv      = (const float*)d_in[8];
    const float* ee      = (const float*)d_in[9];
    const float* Wo      = (const float*)d_in[10];
    const float* bo      = (const float*)d_in[11];
    float* out = (float*)d_out;

    char* ws = (char*)d_ws;
    size_t off = 0;
    auto alloc = [&](size_t bytes) -> void* {
        void* p = ws + off;
        off = (off + bytes + 255) & ~(size_t)255;
        return p;
    };
    float* Q   = (float*)alloc((size_t)N_NODES * HID * sizeof(float));
    float* Kb  = (float*)alloc((size_t)N_NODES * HID * sizeof(float));
    float* V   = (float*)alloc((size_t)N_NODES * HID * sizeof(float));
    float* acc = (float*)alloc((size_t)N_NODES * HID * sizeof(float));
    float* cnt = (float*)alloc((size_t)N_NODES * sizeof(float));

    hipMemsetAsync(acc, 0, (size_t)N_NODES * HID * sizeof(float), stream);
    hipMemsetAsync(cnt, 0, (size_t)N_NODES * sizeof(float), stream);

    const dim3 blk(256);

    // QKV projections: C[50000x256] = nf[50000x128] @ W^T + b
    const dim3 gq(HID / TILE, (N_NODES + TILE - 1) / TILE);
    gemm_bt_kernel<<<gq, blk, 0, stream>>>(nf, Wq, bq, nullptr, Q,  N_NODES, HID, IN_DIM);
    gemm_bt_kernel<<<gq, blk, 0, stream>>>(nf, Wk, bk, nullptr, Kb, N_NODES, HID, IN_DIM);
    gemm_bt_kernel<<<gq, blk, 0, stream>>>(nf, Wv, bv, nullptr, V,  N_NODES, HID, IN_DIM);

    // Per-edge attention + scatter
    edge_attn_kernel<<<dim3((N_EDGES + 3) / 4), blk, 0, stream>>>(
        edges, etypes, (const float4*)Q, (const float4*)Kb, (const float4*)V,
        (const float4*)ee, acc, cnt);

    // Output projection with per-row count*bo bias:
    // out[50000x128] = acc[50000x256] @ Wo^T + cnt[m]*bo
    const dim3 go(IN_DIM / TILE, (N_NODES + TILE - 1) / TILE);
    gemm_bt_kernel<<<go, blk, 0, stream>>>(acc, Wo, bo, cnt, out, N_NODES, IN_DIM, HID);
}

// Round 2
// 764.119 us; speedup vs baseline: 1.6835x; 1.6835x over previous
//
#include <hip/hip_runtime.h>

#define N_NODES 50000
#define N_EDGES 300000
#define IN_DIM 128
#define HID 256
#define NHEADS 8
#define HDIM 32

// ---------------------------------------------------------------------------
// Generic tiled fp32 GEMM: C[M x N] = A[M x K] @ B[N x K]^T + rowscale[m]*bias[n]
// ---------------------------------------------------------------------------
constexpr int TILE = 64;
constexpr int KCHUNK = 64;
constexpr int LDT = 68;

__global__ __launch_bounds__(256)
void gemm_bt_kernel(const float* __restrict__ A, const float* __restrict__ B,
                    const float* __restrict__ bias, const float* __restrict__ rowscale,
                    float* __restrict__ C, int M, int N, int K)
{
    __shared__ float As[KCHUNK * LDT];
    __shared__ float Bs[KCHUNK * LDT];
    const int t  = threadIdx.x;
    const int tx = t & 15;
    const int ty = t >> 4;
    const int m0 = blockIdx.y * TILE;
    const int n0 = blockIdx.x * TILE;

    float c[4][4] = {};

    const int r  = t >> 2;
    const int kb = (t & 3) * 16;

    for (int kc = 0; kc < K; kc += KCHUNK) {
        #pragma unroll
        for (int ii = 0; ii < 4; ++ii) {
            const int k = kb + ii * 4;
            float4 v = make_float4(0.f, 0.f, 0.f, 0.f);
            if (m0 + r < M)
                v = *reinterpret_cast<const float4*>(&A[(size_t)(m0 + r) * K + kc + k]);
            As[(k + 0) * LDT + r] = v.x;
            As[(k + 1) * LDT + r] = v.y;
            As[(k + 2) * LDT + r] = v.z;
            As[(k + 3) * LDT + r] = v.w;
        }
        #pragma unroll
        for (int ii = 0; ii < 4; ++ii) {
            const int k = kb + ii * 4;
            float4 v = *reinterpret_cast<const float4*>(&B[(size_t)(n0 + r) * K + kc + k]);
            Bs[(k + 0) * LDT + r] = v.x;
            Bs[(k + 1) * LDT + r] = v.y;
            Bs[(k + 2) * LDT + r] = v.z;
            Bs[(k + 3) * LDT + r] = v.w;
        }
        __syncthreads();

        #pragma unroll 4
        for (int k = 0; k < KCHUNK; ++k) {
            const float4 a4 = *reinterpret_cast<const float4*>(&As[k * LDT + ty * 4]);
            const float4 b4 = *reinterpret_cast<const float4*>(&Bs[k * LDT + tx * 4]);
            const float av[4] = {a4.x, a4.y, a4.z, a4.w};
            const float bv[4] = {b4.x, b4.y, b4.z, b4.w};
            #pragma unroll
            for (int i = 0; i < 4; ++i)
                #pragma unroll
                for (int j = 0; j < 4; ++j)
                    c[i][j] += av[i] * bv[j];
        }
        __syncthreads();
    }

    #pragma unroll
    for (int i = 0; i < 4; ++i) {
        const int m = m0 + ty * 4 + i;
        if (m >= M) break;
        const float rs = rowscale ? rowscale[m] : 1.0f;
        #pragma unroll
        for (int j = 0; j < 4; ++j) {
            const int n = n0 + tx * 4 + j;
            C[(size_t)m * N + n] = c[i][j] + rs * bias[n];
        }
    }
}

// ---------------------------------------------------------------------------
// CSR build: histogram -> scan -> scatter edge ids
// ---------------------------------------------------------------------------
__global__ __launch_bounds__(256)
void hist_kernel(const int* __restrict__ edges, int* __restrict__ deg)
{
    const int e = blockIdx.x * 256 + threadIdx.x;
    if (e < N_EDGES) atomicAdd(&deg[edges[2 * e]], 1);
}

__global__ __launch_bounds__(1024)
void scan_kernel(const int* __restrict__ deg, int* __restrict__ rowStart,
                 int* __restrict__ cursor, float* __restrict__ cntF)
{
    __shared__ int lds[1024];
    const int t = threadIdx.x;
    const int CH = (N_NODES + 1023) / 1024; // 49
    const int lo = t * CH;
    const int hi = min(lo + CH, N_NODES);
    int s = 0;
    for (int i = lo; i < hi; ++i) s += deg[i];
    lds[t] = s;
    __syncthreads();
    for (int offs = 1; offs < 1024; offs <<= 1) {
        const int v = (t >= offs) ? lds[t - offs] : 0;
        __syncthreads();
        lds[t] += v;
        __syncthreads();
    }
    int base = (t == 0) ? 0 : lds[t - 1];
    for (int i = lo; i < hi; ++i) {
        const int d = deg[i];
        rowStart[i] = base;
        cursor[i]   = base;
        cntF[i]     = (float)d;
        base += d;
    }
    if (t == 1023) rowStart[N_NODES] = base;
}

__global__ __launch_bounds__(256)
void scatter_kernel(const int* __restrict__ edges, int* __restrict__ cursor,
                    int* __restrict__ eid)
{
    const int e = blockIdx.x * 256 + threadIdx.x;
    if (e < N_EDGES) {
        const int pos = atomicAdd(&cursor[edges[2 * e]], 1);
        eid[pos] = e;
    }
}

// ---------------------------------------------------------------------------
// Gather attention: one wave per src node. Accumulator lives in registers
// (float4 per lane = 256 floats per wave); single coalesced write per node.
// lane l: h = l>>3 (query head), g/dd = l&7.
// ---------------------------------------------------------------------------
__global__ __launch_bounds__(256)
void node_gather_kernel(const int* __restrict__ edges, const int* __restrict__ etypes,
                        const int* __restrict__ rowStart, const int* __restrict__ eid,
                        const float4* __restrict__ Q4, const float4* __restrict__ K4,
                        const float4* __restrict__ V4, const float4* __restrict__ EE4,
                        float4* __restrict__ acc4)
{
    const int lane = threadIdx.x & 63;
    const int n = blockIdx.x * 4 + (threadIdx.x >> 6);
    if (n >= N_NODES) return;
    const int h = lane >> 3;
    const int g = lane & 7;
    const int dd = lane & 7;

    float4 q[8];
    #pragma unroll
    for (int d4 = 0; d4 < 8; ++d4)
        q[d4] = Q4[(size_t)n * 64 + h * 8 + d4];

    float4 macc = make_float4(0.f, 0.f, 0.f, 0.f);
    const int lo = rowStart[n];
    const int hi = rowStart[n + 1];

    for (int idx = lo; idx < hi; ++idx) {
        const int e   = eid[idx];
        const int tgt = edges[2 * e + 1];
        const int et  = etypes[e];

        // scores: dot32(Q[h], K[tgt][g]) * scale
        float s = 0.f;
        #pragma unroll
        for (int d4 = 0; d4 < 8; ++d4) {
            const float4 k4 = K4[(size_t)tgt * 64 + g * 8 + d4];
            s += q[d4].x * k4.x + q[d4].y * k4.y + q[d4].z * k4.z + q[d4].w * k4.w;
        }
        s *= 0.17677669529663687f;

        // softmax over g (8-lane groups)
        float m = s;
        m = fmaxf(m, __shfl_xor(m, 1));
        m = fmaxf(m, __shfl_xor(m, 2));
        m = fmaxf(m, __shfl_xor(m, 4));
        const float p = __expf(s - m);
        float sum = p;
        sum += __shfl_xor(sum, 1);
        sum += __shfl_xor(sum, 2);
        sum += __shfl_xor(sum, 4);
        const float a = p / sum;

        // msg accumulate: lane handles float4 slot `lane` of the 256-dim row
        #pragma unroll
        for (int gg = 0; gg < 8; ++gg) {
            const float ag = __shfl(a, (lane & 56) | gg);
            const float4 v4 = V4[(size_t)tgt * 64 + gg * 8 + dd];
            macc.x += ag * v4.x; macc.y += ag * v4.y;
            macc.z += ag * v4.z; macc.w += ag * v4.w;
        }

        // edge-type embedding
        const float4 e4 = EE4[(size_t)et * 64 + lane];
        macc.x += e4.x; macc.y += e4.y; macc.z += e4.z; macc.w += e4.w;
    }

    acc4[(size_t)n * 64 + lane] = macc;
}

// ---------------------------------------------------------------------------
extern "C" void kernel_launch(void* const* d_in, const int* in_sizes, int n_in,
                              void* d_out, int out_size, void* d_ws, size_t ws_size,
                              hipStream_t stream)
{
    const float* nf      = (const float*)d_in[0];
    const int*   edges   = (const int*)d_in[1];
    const int*   etypes  = (const int*)d_in[2];
    const float* Wq      = (const float*)d_in[3];
    const float* bq      = (const float*)d_in[4];
    const float* Wk      = (const float*)d_in[5];
    const float* bk      = (const float*)d_in[6];
    const float* Wv      = (const float*)d_in[7];
    const float* bv      = (const float*)d_in[8];
    const float* ee      = (const float*)d_in[9];
    const float* Wo      = (const float*)d_in[10];
    const float* bo      = (const float*)d_in[11];
    float* out = (float*)d_out;

    char* ws = (char*)d_ws;
    size_t off = 0;
    auto alloc = [&](size_t bytes) -> void* {
        void* p = ws + off;
        off = (off + bytes + 255) & ~(size_t)255;
        return p;
    };
    float* Q    = (float*)alloc((size_t)N_NODES * HID * sizeof(float));
    float* Kb   = (float*)alloc((size_t)N_NODES * HID * sizeof(float));
    float* V    = (float*)alloc((size_t)N_NODES * HID * sizeof(float));
    float* acc  = (float*)alloc((size_t)N_NODES * HID * sizeof(float));
    float* cntF = (float*)alloc((size_t)N_NODES * sizeof(float));
    int*   deg  = (int*)alloc((size_t)N_NODES * sizeof(int));
    int*   rowS = (int*)alloc((size_t)(N_NODES + 1) * sizeof(int));
    int*   curs = (int*)alloc((size_t)N_NODES * sizeof(int));
    int*   eid  = (int*)alloc((size_t)N_EDGES * sizeof(int));

    const dim3 blk(256);

    // --- CSR build ---
    hipMemsetAsync(deg, 0, (size_t)N_NODES * sizeof(int), stream);
    hist_kernel<<<dim3((N_EDGES + 255) / 256), blk, 0, stream>>>(edges, deg);
    scan_kernel<<<dim3(1), dim3(1024), 0, stream>>>(deg, rowS, curs, cntF);
    scatter_kernel<<<dim3((N_EDGES + 255) / 256), blk, 0, stream>>>(edges, curs, eid);

    // --- QKV projections ---
    const dim3 gq(HID / TILE, (N_NODES + TILE - 1) / TILE);
    gemm_bt_kernel<<<gq, blk, 0, stream>>>(nf, Wq, bq, nullptr, Q,  N_NODES, HID, IN_DIM);
    gemm_bt_kernel<<<gq, blk, 0, stream>>>(nf, Wk, bk, nullptr, Kb, N_NODES, HID, IN_DIM);
    gemm_bt_kernel<<<gq, blk, 0, stream>>>(nf, Wv, bv, nullptr, V,  N_NODES, HID, IN_DIM);

    // --- gather attention (wave per node, register accumulator) ---
    node_gather_kernel<<<dim3((N_NODES + 3) / 4), blk, 0, stream>>>(
        edges, etypes, rowS, eid, (const float4*)Q, (const float4*)Kb,
        (const float4*)V, (const float4*)ee, (float4*)acc);

    // --- output projection: out = acc @ Wo^T + cnt[m]*bo ---
    const dim3 go(IN_DIM / TILE, (N_NODES + TILE - 1) / TILE);
    gemm_bt_kernel<<<go, blk, 0, stream>>>(acc, Wo, bo, cntF, out, N_NODES, IN_DIM, HID);
}

// Round 3
// 573.649 us; speedup vs baseline: 2.2425x; 1.3320x over previous
//
#include <hip/hip_runtime.h>

#define N_NODES 50000
#define N_EDGES 300000
#define IN_DIM 128
#define HID 256
#define NHEADS 8
#define HDIM 32

__device__ __forceinline__ float bflo(unsigned int u) { return __uint_as_float(u << 16); }
__device__ __forceinline__ float bfhi(unsigned int u) { return __uint_as_float(u & 0xFFFF0000u); }
__device__ __forceinline__ unsigned short f2bf(float x) {
    unsigned int u = __float_as_uint(x);
    unsigned int r = (u + 0x7FFFu + ((u >> 16) & 1u)) >> 16;
    return (unsigned short)r;
}

// ---------------------------------------------------------------------------
// Tiled fp32 GEMM: C[M x N] = A[M x K] @ B[N x K]^T + rowscale[m]*bias[n]
// OUT_BF16: store C as bf16 (RNE) instead of fp32.
// ---------------------------------------------------------------------------
constexpr int TILE = 64;
constexpr int KCHUNK = 64;
constexpr int LDT = 68;

template <int OUT_BF16>
__global__ __launch_bounds__(256)
void gemm_bt_kernel(const float* __restrict__ A, const float* __restrict__ B,
                    const float* __restrict__ bias, const float* __restrict__ rowscale,
                    void* __restrict__ Cv, int M, int N, int K)
{
    __shared__ float As[KCHUNK * LDT];
    __shared__ float Bs[KCHUNK * LDT];
    const int t  = threadIdx.x;
    const int tx = t & 15;
    const int ty = t >> 4;
    const int m0 = blockIdx.y * TILE;
    const int n0 = blockIdx.x * TILE;

    float c[4][4] = {};

    const int r  = t >> 2;
    const int kb = (t & 3) * 16;

    for (int kc = 0; kc < K; kc += KCHUNK) {
        #pragma unroll
        for (int ii = 0; ii < 4; ++ii) {
            const int k = kb + ii * 4;
            float4 v = make_float4(0.f, 0.f, 0.f, 0.f);
            if (m0 + r < M)
                v = *reinterpret_cast<const float4*>(&A[(size_t)(m0 + r) * K + kc + k]);
            As[(k + 0) * LDT + r] = v.x;
            As[(k + 1) * LDT + r] = v.y;
            As[(k + 2) * LDT + r] = v.z;
            As[(k + 3) * LDT + r] = v.w;
        }
        #pragma unroll
        for (int ii = 0; ii < 4; ++ii) {
            const int k = kb + ii * 4;
            float4 v = *reinterpret_cast<const float4*>(&B[(size_t)(n0 + r) * K + kc + k]);
            Bs[(k + 0) * LDT + r] = v.x;
            Bs[(k + 1) * LDT + r] = v.y;
            Bs[(k + 2) * LDT + r] = v.z;
            Bs[(k + 3) * LDT + r] = v.w;
        }
        __syncthreads();

        #pragma unroll 4
        for (int k = 0; k < KCHUNK; ++k) {
            const float4 a4 = *reinterpret_cast<const float4*>(&As[k * LDT + ty * 4]);
            const float4 b4 = *reinterpret_cast<const float4*>(&Bs[k * LDT + tx * 4]);
            const float av[4] = {a4.x, a4.y, a4.z, a4.w};
            const float bv[4] = {b4.x, b4.y, b4.z, b4.w};
            #pragma unroll
            for (int i = 0; i < 4; ++i)
                #pragma unroll
                for (int j = 0; j < 4; ++j)
                    c[i][j] += av[i] * bv[j];
        }
        __syncthreads();
    }

    #pragma unroll
    for (int i = 0; i < 4; ++i) {
        const int m = m0 + ty * 4 + i;
        if (m >= M) break;
        const float rs = rowscale ? rowscale[m] : 1.0f;
        float o[4];
        #pragma unroll
        for (int j = 0; j < 4; ++j)
            o[j] = c[i][j] + rs * bias[n0 + tx * 4 + j];
        if (OUT_BF16) {
            ushort4 ob;
            ob.x = f2bf(o[0]); ob.y = f2bf(o[1]); ob.z = f2bf(o[2]); ob.w = f2bf(o[3]);
            *reinterpret_cast<ushort4*>(
                &((unsigned short*)Cv)[(size_t)m * N + n0 + tx * 4]) = ob;
        } else {
            *reinterpret_cast<float4*>(&((float*)Cv)[(size_t)m * N + n0 + tx * 4]) =
                make_float4(o[0], o[1], o[2], o[3]);
        }
    }
}

// ---------------------------------------------------------------------------
// CSR build: histogram -> scan -> scatter packed (tgt | etype<<20)
// ---------------------------------------------------------------------------
__global__ __launch_bounds__(256)
void hist_kernel(const int* __restrict__ edges, int* __restrict__ deg)
{
    const int e = blockIdx.x * 256 + threadIdx.x;
    if (e < N_EDGES) atomicAdd(&deg[edges[2 * e]], 1);
}

__global__ __launch_bounds__(1024)
void scan_kernel(const int* __restrict__ deg, int* __restrict__ rowStart,
                 int* __restrict__ cursor, float* __restrict__ cntF)
{
    __shared__ int lds[1024];
    const int t = threadIdx.x;
    const int CH = (N_NODES + 1023) / 1024;
    const int lo = t * CH;
    const int hi = min(lo + CH, N_NODES);
    int s = 0;
    for (int i = lo; i < hi; ++i) s += deg[i];
    lds[t] = s;
    __syncthreads();
    for (int offs = 1; offs < 1024; offs <<= 1) {
        const int v = (t >= offs) ? lds[t - offs] : 0;
        __syncthreads();
        lds[t] += v;
        __syncthreads();
    }
    int base = (t == 0) ? 0 : lds[t - 1];
    for (int i = lo; i < hi; ++i) {
        const int d = deg[i];
        rowStart[i] = base;
        cursor[i]   = base;
        cntF[i]     = (float)d;
        base += d;
    }
    if (t == 1023) rowStart[N_NODES] = base;
}

__global__ __launch_bounds__(256)
void scatter_kernel(const int* __restrict__ edges, const int* __restrict__ etypes,
                    int* __restrict__ cursor, int* __restrict__ packed)
{
    const int e = blockIdx.x * 256 + threadIdx.x;
    if (e < N_EDGES) {
        const int pos = atomicAdd(&cursor[edges[2 * e]], 1);
        packed[pos] = edges[2 * e + 1] | (etypes[e] << 20);
    }
}

// ---------------------------------------------------------------------------
// Gather attention over bf16 Q/K/V. One wave per src node.
// lane l: h = l>>3 (query head), g = dd = l&7.
// ---------------------------------------------------------------------------
__device__ __forceinline__ float dot8(const float* __restrict__ q, uint4 u)
{
    float s;
    s  = q[0] * bflo(u.x);
    s += q[1] * bfhi(u.x);
    s += q[2] * bflo(u.y);
    s += q[3] * bfhi(u.y);
    s += q[4] * bflo(u.z);
    s += q[5] * bfhi(u.z);
    s += q[6] * bflo(u.w);
    s += q[7] * bfhi(u.w);
    return s;
}

__global__ __launch_bounds__(256)
void node_gather_kernel(const int* __restrict__ packed, const int* __restrict__ rowStart,
                        const uint4* __restrict__ Qb, const uint4* __restrict__ Kb,
                        const uint2* __restrict__ Vb, const float4* __restrict__ EE4,
                        float4* __restrict__ acc4)
{
    const int lane = threadIdx.x & 63;
    const int n = blockIdx.x * 4 + (threadIdx.x >> 6);
    if (n >= N_NODES) return;
    const int h  = lane >> 3;
    const int g  = lane & 7;
    const int dd = lane & 7;

    // Q head h -> 32 fp32 in registers
    float q[32];
    #pragma unroll
    for (int d = 0; d < 4; ++d) {
        const uint4 u = Qb[(size_t)n * 32 + h * 4 + d];
        q[d * 8 + 0] = bflo(u.x); q[d * 8 + 1] = bfhi(u.x);
        q[d * 8 + 2] = bflo(u.y); q[d * 8 + 3] = bfhi(u.y);
        q[d * 8 + 4] = bflo(u.z); q[d * 8 + 5] = bfhi(u.z);
        q[d * 8 + 6] = bflo(u.w); q[d * 8 + 7] = bfhi(u.w);
    }

    float4 macc = make_float4(0.f, 0.f, 0.f, 0.f);
    int cnt0 = 0, cnt1 = 0, cnt2 = 0;

    const int lo = rowStart[n];
    const int hi = rowStart[n + 1];
    int idx = lo;

    for (; idx + 2 <= hi; idx += 2) {
        const int p0 = packed[idx];
        const int p1 = packed[idx + 1];
        const int t0 = p0 & 0xFFFFF;
        const int t1 = p1 & 0xFFFFF;
        const int e0 = p0 >> 20;
        const int e1 = p1 >> 20;
        cnt0 += (e0 == 0) + (e1 == 0);
        cnt1 += (e0 == 1) + (e1 == 1);
        cnt2 += (e0 == 2) + (e1 == 2);

        // scores for both edges (loads interleaved)
        float s0 = 0.f, s1 = 0.f;
        #pragma unroll
        for (int d = 0; d < 4; ++d) {
            const uint4 k0 = Kb[(size_t)t0 * 32 + g * 4 + d];
            const uint4 k1 = Kb[(size_t)t1 * 32 + g * 4 + d];
            s0 += dot8(&q[d * 8], k0);
            s1 += dot8(&q[d * 8], k1);
        }
        s0 *= 0.17677669529663687f;
        s1 *= 0.17677669529663687f;

        // softmax over g (8-lane groups), both edges
        float m0 = s0, m1 = s1;
        m0 = fmaxf(m0, __shfl_xor(m0, 1)); m1 = fmaxf(m1, __shfl_xor(m1, 1));
        m0 = fmaxf(m0, __shfl_xor(m0, 2)); m1 = fmaxf(m1, __shfl_xor(m1, 2));
        m0 = fmaxf(m0, __shfl_xor(m0, 4)); m1 = fmaxf(m1, __shfl_xor(m1, 4));
        float p0f = __expf(s0 - m0), p1f = __expf(s1 - m1);
        float u0 = p0f, u1 = p1f;
        u0 += __shfl_xor(u0, 1); u1 += __shfl_xor(u1, 1);
        u0 += __shfl_xor(u0, 2); u1 += __shfl_xor(u1, 2);
        u0 += __shfl_xor(u0, 4); u1 += __shfl_xor(u1, 4);
        const float a0 = p0f / u0;
        const float a1 = p1f / u1;

        // V accumulate, both edges
        #pragma unroll
        for (int gg = 0; gg < 8; ++gg) {
            const float ag0 = __shfl(a0, (lane & 56) | gg);
            const float ag1 = __shfl(a1, (lane & 56) | gg);
            const uint2 v0 = Vb[(size_t)t0 * 64 + gg * 8 + dd];
            const uint2 v1 = Vb[(size_t)t1 * 64 + gg * 8 + dd];
            macc.x += ag0 * bflo(v0.x) + ag1 * bflo(v1.x);
            macc.y += ag0 * bfhi(v0.x) + ag1 * bfhi(v1.x);
            macc.z += ag0 * bflo(v0.y) + ag1 * bflo(v1.y);
            macc.w += ag0 * bfhi(v0.y) + ag1 * bfhi(v1.y);
        }
    }

    if (idx < hi) {
        const int p0 = packed[idx];
        const int t0 = p0 & 0xFFFFF;
        const int e0 = p0 >> 20;
        cnt0 += (e0 == 0); cnt1 += (e0 == 1); cnt2 += (e0 == 2);

        float s0 = 0.f;
        #pragma unroll
        for (int d = 0; d < 4; ++d)
            s0 += dot8(&q[d * 8], Kb[(size_t)t0 * 32 + g * 4 + d]);
        s0 *= 0.17677669529663687f;

        float m0 = s0;
        m0 = fmaxf(m0, __shfl_xor(m0, 1));
        m0 = fmaxf(m0, __shfl_xor(m0, 2));
        m0 = fmaxf(m0, __shfl_xor(m0, 4));
        float p0f = __expf(s0 - m0);
        float u0 = p0f;
        u0 += __shfl_xor(u0, 1);
        u0 += __shfl_xor(u0, 2);
        u0 += __shfl_xor(u0, 4);
        const float a0 = p0f / u0;

        #pragma unroll
        for (int gg = 0; gg < 8; ++gg) {
            const float ag0 = __shfl(a0, (lane & 56) | gg);
            const uint2 v0 = Vb[(size_t)t0 * 64 + gg * 8 + dd];
            macc.x += ag0 * bflo(v0.x);
            macc.y += ag0 * bfhi(v0.x);
            macc.z += ag0 * bflo(v0.y);
            macc.w += ag0 * bfhi(v0.y);
        }
    }

    // hoisted edge-type embedding: sum_e ee[et[e]] = cnt_t * ee[t]
    const float4 ee0 = EE4[0 * 64 + lane];
    const float4 ee1 = EE4[1 * 64 + lane];
    const float4 ee2 = EE4[2 * 64 + lane];
    const float c0 = (float)cnt0, c1 = (float)cnt1, c2 = (float)cnt2;
    macc.x += c0 * ee0.x + c1 * ee1.x + c2 * ee2.x;
    macc.y += c0 * ee0.y + c1 * ee1.y + c2 * ee2.y;
    macc.z += c0 * ee0.z + c1 * ee1.z + c2 * ee2.z;
    macc.w += c0 * ee0.w + c1 * ee1.w + c2 * ee2.w;

    acc4[(size_t)n * 64 + lane] = macc;
}

// ---------------------------------------------------------------------------
extern "C" void kernel_launch(void* const* d_in, const int* in_sizes, int n_in,
                              void* d_out, int out_size, void* d_ws, size_t ws_size,
                              hipStream_t stream)
{
    const float* nf      = (const float*)d_in[0];
    const int*   edges   = (const int*)d_in[1];
    const int*   etypes  = (const int*)d_in[2];
    const float* Wq      = (const float*)d_in[3];
    const float* bq      = (const float*)d_in[4];
    const float* Wk      = (const float*)d_in[5];
    const float* bk      = (const float*)d_in[6];
    const float* Wv      = (const float*)d_in[7];
    const float* bv      = (const float*)d_in[8];
    const float* ee      = (const float*)d_in[9];
    const float* Wo      = (const float*)d_in[10];
    const float* bo      = (const float*)d_in[11];
    float* out = (float*)d_out;

    char* ws = (char*)d_ws;
    size_t off = 0;
    auto alloc = [&](size_t bytes) -> void* {
        void* p = ws + off;
        off = (off + bytes + 255) & ~(size_t)255;
        return p;
    };
    unsigned short* Qb = (unsigned short*)alloc((size_t)N_NODES * HID * 2);
    unsigned short* Kb = (unsigned short*)alloc((size_t)N_NODES * HID * 2);
    unsigned short* Vb = (unsigned short*)alloc((size_t)N_NODES * HID * 2);
    float* acc  = (float*)alloc((size_t)N_NODES * HID * sizeof(float));
    float* cntF = (float*)alloc((size_t)N_NODES * sizeof(float));
    int*   deg  = (int*)alloc((size_t)N_NODES * sizeof(int));
    int*   rowS = (int*)alloc((size_t)(N_NODES + 1) * sizeof(int));
    int*   curs = (int*)alloc((size_t)N_NODES * sizeof(int));
    int*   pck  = (int*)alloc((size_t)N_EDGES * sizeof(int));

    const dim3 blk(256);

    // --- CSR build ---
    hipMemsetAsync(deg, 0, (size_t)N_NODES * sizeof(int), stream);
    hist_kernel<<<dim3((N_EDGES + 255) / 256), blk, 0, stream>>>(edges, deg);
    scan_kernel<<<dim3(1), dim3(1024), 0, stream>>>(deg, rowS, curs, cntF);
    scatter_kernel<<<dim3((N_EDGES + 255) / 256), blk, 0, stream>>>(edges, etypes, curs, pck);

    // --- QKV projections (bf16 output) ---
    const dim3 gq(HID / TILE, (N_NODES + TILE - 1) / TILE);
    gemm_bt_kernel<1><<<gq, blk, 0, stream>>>(nf, Wq, bq, nullptr, Qb, N_NODES, HID, IN_DIM);
    gemm_bt_kernel<1><<<gq, blk, 0, stream>>>(nf, Wk, bk, nullptr, Kb, N_NODES, HID, IN_DIM);
    gemm_bt_kernel<1><<<gq, blk, 0, stream>>>(nf, Wv, bv, nullptr, Vb, N_NODES, HID, IN_DIM);

    // --- gather attention (wave per node, bf16 gathers, register accumulator) ---
    node_gather_kernel<<<dim3((N_NODES + 3) / 4), blk, 0, stream>>>(
        pck, rowS, (const uint4*)Qb, (const uint4*)Kb, (const uint2*)Vb,
        (const float4*)ee, (float4*)acc);

    // --- output projection: out = acc @ Wo^T + cnt[m]*bo ---
    const dim3 go(IN_DIM / TILE, (N_NODES + TILE - 1) / TILE);
    gemm_bt_kernel<0><<<go, blk, 0, stream>>>(acc, Wo, bo, cntF, out, N_NODES, IN_DIM, HID);
}

// Round 4
// 453.422 us; speedup vs baseline: 2.8371x; 1.2652x over previous
//
#include <hip/hip_runtime.h>

#define N_NODES 50000
#define N_EDGES 300000
#define IN_DIM 128
#define HID 256
#define M_PAD 50048   // 391 * 128

typedef __attribute__((ext_vector_type(8))) short bf16x8;
typedef __attribute__((ext_vector_type(4))) float f32x4;

__device__ __forceinline__ float bflo(unsigned int u) { return __uint_as_float(u << 16); }
__device__ __forceinline__ float bfhi(unsigned int u) { return __uint_as_float(u & 0xFFFF0000u); }
__device__ __forceinline__ float bf2f(unsigned short h) { return __uint_as_float(((unsigned int)h) << 16); }
__device__ __forceinline__ unsigned short f2bf(float x) {
    unsigned int u = __float_as_uint(x);
    unsigned int r = (u + 0x7FFFu + ((u >> 16) & 1u)) >> 16;
    return (unsigned short)r;
}

typedef __attribute__((address_space(3))) unsigned int lds_uint;
typedef const __attribute__((address_space(1))) unsigned int glb_uint;
__device__ __forceinline__ void gld16(const void* g, void* l) {
    __builtin_amdgcn_global_load_lds((glb_uint*)g, (lds_uint*)l, 16, 0, 0);
}

// ---------------------------------------------------------------------------
// MFMA GEMM: C[M_PAD x NCOLS] = A2[M_PAD x K2](bf16) @ B2[NCOLS x K2](bf16)^T
// 128x128 tile, BK=64, 4 waves (2x2 of 64x64), 16x16x32 bf16 MFMA.
// MODE 0: NCOLS=768, scatter columns to Qb/Kb/Vb (bf16) + biasCat.
// MODE 1: NCOLS=128, fp32 out + rowscale[m]*bias[n].
// ---------------------------------------------------------------------------
template <int MODE, int K2, int NCOLS>
__global__ __launch_bounds__(256)
void mfma_gemm(const unsigned short* __restrict__ A2, const unsigned short* __restrict__ B2,
               const float* __restrict__ biasCat, const float* __restrict__ rowscale,
               unsigned short* __restrict__ Qb, unsigned short* __restrict__ Kb,
               unsigned short* __restrict__ Vb, float* __restrict__ Cout, int M)
{
    __shared__ unsigned short As[128 * 64];
    __shared__ unsigned short Bs[128 * 64];
    const int t = threadIdx.x;
    const int w = t >> 6;
    const int lane = t & 63;
    const int m0 = blockIdx.y * 128;
    const int n0 = blockIdx.x * 128;
    const int wm = (w >> 1) * 64;
    const int wn = (w & 1) * 64;

    f32x4 acc[4][4] = {};

    for (int kc = 0; kc < K2; kc += 64) {
        #pragma unroll
        for (int i = 0; i < 4; ++i) {
            const int chunk = i * 4 + w;          // 0..15 wave-chunks of 1024B
            const int o = (chunk * 64 + lane) * 16; // byte offset in 16KB tile
            const int row = o >> 7;                // 128B per row (64 bf16)
            const int cb = o & 127;
            const char* gA = (const char*)A2 + ((size_t)(m0 + row) * K2 + kc) * 2 + cb;
            const char* gB = (const char*)B2 + ((size_t)(n0 + row) * K2 + kc) * 2 + cb;
            gld16(gA, (char*)As + chunk * 1024);
            gld16(gB, (char*)Bs + chunk * 1024);
        }
        __syncthreads();

        bf16x8 af[4][2], bfr[4][2];
        #pragma unroll
        for (int mi = 0; mi < 4; ++mi)
            #pragma unroll
            for (int kk = 0; kk < 2; ++kk)
                af[mi][kk] = *(const bf16x8*)&As[(wm + mi * 16 + (lane & 15)) * 64 + kk * 32 + (lane >> 4) * 8];
        #pragma unroll
        for (int ni = 0; ni < 4; ++ni)
            #pragma unroll
            for (int kk = 0; kk < 2; ++kk)
                bfr[ni][kk] = *(const bf16x8*)&Bs[(wn + ni * 16 + (lane & 15)) * 64 + kk * 32 + (lane >> 4) * 8];

        #pragma unroll
        for (int mi = 0; mi < 4; ++mi)
            #pragma unroll
            for (int ni = 0; ni < 4; ++ni)
                #pragma unroll
                for (int kk = 0; kk < 2; ++kk)
                    acc[mi][ni] = __builtin_amdgcn_mfma_f32_16x16x32_bf16(
                        af[mi][kk], bfr[ni][kk], acc[mi][ni], 0, 0, 0);
        __syncthreads();
    }

    if (MODE == 0) {
        #pragma unroll
        for (int ni = 0; ni < 4; ++ni) {
            const int col = n0 + wn + ni * 16 + (lane & 15);
            const float bv_ = biasCat[col];
            unsigned short* dst = (col < 256) ? Qb : (col < 512) ? Kb : Vb;
            const int c = col & 255;
            #pragma unroll
            for (int mi = 0; mi < 4; ++mi) {
                #pragma unroll
                for (int j = 0; j < 4; ++j) {
                    const int row = m0 + wm + mi * 16 + (lane >> 4) * 4 + j;
                    if (row < M) dst[(size_t)row * 256 + c] = f2bf(acc[mi][ni][j] + bv_);
                }
            }
        }
    } else {
        #pragma unroll
        for (int mi = 0; mi < 4; ++mi) {
            #pragma unroll
            for (int j = 0; j < 4; ++j) {
                const int row = m0 + wm + mi * 16 + (lane >> 4) * 4 + j;
                if (row < M) {
                    const float rs = rowscale[row];
                    #pragma unroll
                    for (int ni = 0; ni < 4; ++ni) {
                        const int col = wn + ni * 16 + (lane & 15);
                        Cout[(size_t)row * NCOLS + col] = acc[mi][ni][j] + rs * biasCat[col];
                    }
                }
            }
        }
    }
}

// ---------------------------------------------------------------------------
// Conversions
// ---------------------------------------------------------------------------
__global__ __launch_bounds__(256)
void conv_nf_kernel(const float4* __restrict__ nf4, unsigned short* __restrict__ A2)
{
    const int tid = blockIdx.x * 256 + threadIdx.x;
    if (tid >= N_NODES * 32) return;
    const int m = tid >> 5, k4 = (tid & 31) * 4;
    const float4 v = nf4[tid];
    ushort4 hi, lo;
    hi.x = f2bf(v.x); lo.x = f2bf(v.x - bf2f(hi.x));
    hi.y = f2bf(v.y); lo.y = f2bf(v.y - bf2f(hi.y));
    hi.z = f2bf(v.z); lo.z = f2bf(v.z - bf2f(hi.z));
    hi.w = f2bf(v.w); lo.w = f2bf(v.w - bf2f(hi.w));
    *reinterpret_cast<ushort4*>(&A2[(size_t)m * 256 + k4]) = hi;
    *reinterpret_cast<ushort4*>(&A2[(size_t)m * 256 + 128 + k4]) = lo;
}

__global__ __launch_bounds__(256)
void conv_w_kernel(const float* __restrict__ Wq, const float* __restrict__ Wk,
                   const float* __restrict__ Wv, const float* __restrict__ bq,
                   const float* __restrict__ bk, const float* __restrict__ bv,
                   unsigned short* __restrict__ B2, float* __restrict__ biasCat)
{
    const int tid = blockIdx.x * 256 + threadIdx.x;
    if (tid >= 768 * 128) return;
    const int r = tid >> 7, k = tid & 127;
    const float* W = (r < 256) ? Wq : (r < 512) ? Wk : Wv;
    const unsigned short h = f2bf(W[(size_t)(r & 255) * 128 + k]);
    B2[(size_t)r * 256 + k] = h;
    B2[(size_t)r * 256 + 128 + k] = h;
    if (k == 0) {
        const float* b = (r < 256) ? bq : (r < 512) ? bk : bv;
        biasCat[r] = b[r & 255];
    }
}

__global__ __launch_bounds__(256)
void conv_wo_kernel(const float* __restrict__ Wo, unsigned short* __restrict__ B2o)
{
    const int tid = blockIdx.x * 256 + threadIdx.x;
    if (tid >= 128 * 256) return;
    const int r = tid >> 8, k = tid & 255;
    const unsigned short h = f2bf(Wo[(size_t)r * 256 + k]);
    B2o[(size_t)r * 512 + k] = h;
    B2o[(size_t)r * 512 + 256 + k] = h;
}

// ---------------------------------------------------------------------------
// CSR build: histogram -> scan -> scatter packed (tgt | etype<<20)
// ---------------------------------------------------------------------------
__global__ __launch_bounds__(256)
void hist_kernel(const int* __restrict__ edges, int* __restrict__ deg)
{
    const int e = blockIdx.x * 256 + threadIdx.x;
    if (e < N_EDGES) atomicAdd(&deg[edges[2 * e]], 1);
}

__global__ __launch_bounds__(1024)
void scan_kernel(const int* __restrict__ deg, int* __restrict__ rowStart,
                 int* __restrict__ cursor, float* __restrict__ cntF)
{
    __shared__ int lds[1024];
    const int t = threadIdx.x;
    const int CH = (N_NODES + 1023) / 1024;
    const int lo = t * CH;
    const int hi = min(lo + CH, N_NODES);
    int s = 0;
    for (int i = lo; i < hi; ++i) s += deg[i];
    lds[t] = s;
    __syncthreads();
    for (int offs = 1; offs < 1024; offs <<= 1) {
        const int v = (t >= offs) ? lds[t - offs] : 0;
        __syncthreads();
        lds[t] += v;
        __syncthreads();
    }
    int base = (t == 0) ? 0 : lds[t - 1];
    for (int i = lo; i < hi; ++i) {
        const int d = deg[i];
        rowStart[i] = base;
        cursor[i]   = base;
        cntF[i]     = (float)d;
        base += d;
    }
    if (t == 1023) rowStart[N_NODES] = base;
}

__global__ __launch_bounds__(256)
void scatter_kernel(const int* __restrict__ edges, const int* __restrict__ etypes,
                    int* __restrict__ cursor, int* __restrict__ packed)
{
    const int e = blockIdx.x * 256 + threadIdx.x;
    if (e < N_EDGES) {
        const int pos = atomicAdd(&cursor[edges[2 * e]], 1);
        packed[pos] = edges[2 * e + 1] | (etypes[e] << 20);
    }
}

// ---------------------------------------------------------------------------
// Gather attention over bf16 Q/K/V. One wave per src node.
// Writes message row as split bf16 (hi | lo) -> feeds MFMA output GEMM.
// ---------------------------------------------------------------------------
__device__ __forceinline__ float dot8(const float* __restrict__ q, uint4 u)
{
    float s;
    s  = q[0] * bflo(u.x);
    s += q[1] * bfhi(u.x);
    s += q[2] * bflo(u.y);
    s += q[3] * bfhi(u.y);
    s += q[4] * bflo(u.z);
    s += q[5] * bfhi(u.z);
    s += q[6] * bflo(u.w);
    s += q[7] * bfhi(u.w);
    return s;
}

__global__ __launch_bounds__(256)
void node_gather_kernel(const int* __restrict__ packed, const int* __restrict__ rowStart,
                        const uint4* __restrict__ Qb, const uint4* __restrict__ Kb,
                        const uint2* __restrict__ Vb, const float4* __restrict__ EE4,
                        unsigned short* __restrict__ accQ)
{
    const int lane = threadIdx.x & 63;
    const int n = blockIdx.x * 4 + (threadIdx.x >> 6);
    if (n >= N_NODES) return;
    const int h  = lane >> 3;
    const int g  = lane & 7;
    const int dd = lane & 7;

    float q[32];
    #pragma unroll
    for (int d = 0; d < 4; ++d) {
        const uint4 u = Qb[(size_t)n * 32 + h * 4 + d];
        q[d * 8 + 0] = bflo(u.x); q[d * 8 + 1] = bfhi(u.x);
        q[d * 8 + 2] = bflo(u.y); q[d * 8 + 3] = bfhi(u.y);
        q[d * 8 + 4] = bflo(u.z); q[d * 8 + 5] = bfhi(u.z);
        q[d * 8 + 6] = bflo(u.w); q[d * 8 + 7] = bfhi(u.w);
    }

    float4 macc = make_float4(0.f, 0.f, 0.f, 0.f);
    int cnt0 = 0, cnt1 = 0, cnt2 = 0;

    const int lo = rowStart[n];
    const int hi = rowStart[n + 1];
    int idx = lo;

    for (; idx + 2 <= hi; idx += 2) {
        const int p0 = packed[idx];
        const int p1 = packed[idx + 1];
        const int t0 = p0 & 0xFFFFF;
        const int t1 = p1 & 0xFFFFF;
        const int e0 = p0 >> 20;
        const int e1 = p1 >> 20;
        cnt0 += (e0 == 0) + (e1 == 0);
        cnt1 += (e0 == 1) + (e1 == 1);
        cnt2 += (e0 == 2) + (e1 == 2);

        float s0 = 0.f, s1 = 0.f;
        #pragma unroll
        for (int d = 0; d < 4; ++d) {
            const uint4 k0 = Kb[(size_t)t0 * 32 + g * 4 + d];
            const uint4 k1 = Kb[(size_t)t1 * 32 + g * 4 + d];
            s0 += dot8(&q[d * 8], k0);
            s1 += dot8(&q[d * 8], k1);
        }
        s0 *= 0.17677669529663687f;
        s1 *= 0.17677669529663687f;

        float m0 = s0, m1 = s1;
        m0 = fmaxf(m0, __shfl_xor(m0, 1)); m1 = fmaxf(m1, __shfl_xor(m1, 1));
        m0 = fmaxf(m0, __shfl_xor(m0, 2)); m1 = fmaxf(m1, __shfl_xor(m1, 2));
        m0 = fmaxf(m0, __shfl_xor(m0, 4)); m1 = fmaxf(m1, __shfl_xor(m1, 4));
        float p0f = __expf(s0 - m0), p1f = __expf(s1 - m1);
        float u0 = p0f, u1 = p1f;
        u0 += __shfl_xor(u0, 1); u1 += __shfl_xor(u1, 1);
        u0 += __shfl_xor(u0, 2); u1 += __shfl_xor(u1, 2);
        u0 += __shfl_xor(u0, 4); u1 += __shfl_xor(u1, 4);
        const float a0 = p0f / u0;
        const float a1 = p1f / u1;

        #pragma unroll
        for (int gg = 0; gg < 8; ++gg) {
            const float ag0 = __shfl(a0, (lane & 56) | gg);
            const float ag1 = __shfl(a1, (lane & 56) | gg);
            const uint2 v0 = Vb[(size_t)t0 * 64 + gg * 8 + dd];
            const uint2 v1 = Vb[(size_t)t1 * 64 + gg * 8 + dd];
            macc.x += ag0 * bflo(v0.x) + ag1 * bflo(v1.x);
            macc.y += ag0 * bfhi(v0.x) + ag1 * bfhi(v1.x);
            macc.z += ag0 * bflo(v0.y) + ag1 * bflo(v1.y);
            macc.w += ag0 * bfhi(v0.y) + ag1 * bfhi(v1.y);
        }
    }

    if (idx < hi) {
        const int p0 = packed[idx];
        const int t0 = p0 & 0xFFFFF;
        const int e0 = p0 >> 20;
        cnt0 += (e0 == 0); cnt1 += (e0 == 1); cnt2 += (e0 == 2);

        float s0 = 0.f;
        #pragma unroll
        for (int d = 0; d < 4; ++d)
            s0 += dot8(&q[d * 8], Kb[(size_t)t0 * 32 + g * 4 + d]);
        s0 *= 0.17677669529663687f;

        float m0 = s0;
        m0 = fmaxf(m0, __shfl_xor(m0, 1));
        m0 = fmaxf(m0, __shfl_xor(m0, 2));
        m0 = fmaxf(m0, __shfl_xor(m0, 4));
        float p0f = __expf(s0 - m0);
        float u0 = p0f;
        u0 += __shfl_xor(u0, 1);
        u0 += __shfl_xor(u0, 2);
        u0 += __shfl_xor(u0, 4);
        const float a0 = p0f / u0;

        #pragma unroll
        for (int gg = 0; gg < 8; ++gg) {
            const float ag0 = __shfl(a0, (lane & 56) | gg);
            const uint2 v0 = Vb[(size_t)t0 * 64 + gg * 8 + dd];
            macc.x += ag0 * bflo(v0.x);
            macc.y += ag0 * bfhi(v0.x);
            macc.z += ag0 * bflo(v0.y);
            macc.w += ag0 * bfhi(v0.y);
        }
    }

    const float4 ee0 = EE4[0 * 64 + lane];
    const float4 ee1 = EE4[1 * 64 + lane];
    const float4 ee2 = EE4[2 * 64 + lane];
    const float c0 = (float)cnt0, c1 = (float)cnt1, c2 = (float)cnt2;
    macc.x += c0 * ee0.x + c1 * ee1.x + c2 * ee2.x;
    macc.y += c0 * ee0.y + c1 * ee1.y + c2 * ee2.y;
    macc.z += c0 * ee0.z + c1 * ee1.z + c2 * ee2.z;
    macc.w += c0 * ee0.w + c1 * ee1.w + c2 * ee2.w;

    // split store: hi at cols [0,256), lo at cols [256,512)
    ushort4 hi4, lo4;
    hi4.x = f2bf(macc.x); lo4.x = f2bf(macc.x - bf2f(hi4.x));
    hi4.y = f2bf(macc.y); lo4.y = f2bf(macc.y - bf2f(hi4.y));
    hi4.z = f2bf(macc.z); lo4.z = f2bf(macc.z - bf2f(hi4.z));
    hi4.w = f2bf(macc.w); lo4.w = f2bf(macc.w - bf2f(hi4.w));
    *reinterpret_cast<ushort4*>(&accQ[(size_t)n * 512 + lane * 4]) = hi4;
    *reinterpret_cast<ushort4*>(&accQ[(size_t)n * 512 + 256 + lane * 4]) = lo4;
}

// ---------------------------------------------------------------------------
extern "C" void kernel_launch(void* const* d_in, const int* in_sizes, int n_in,
                              void* d_out, int out_size, void* d_ws, size_t ws_size,
                              hipStream_t stream)
{
    const float* nf      = (const float*)d_in[0];
    const int*   edges   = (const int*)d_in[1];
    const int*   etypes  = (const int*)d_in[2];
    const float* Wq      = (const float*)d_in[3];
    const float* bq      = (const float*)d_in[4];
    const float* Wk      = (const float*)d_in[5];
    const float* bk      = (const float*)d_in[6];
    const float* Wv      = (const float*)d_in[7];
    const float* bv      = (const float*)d_in[8];
    const float* ee      = (const float*)d_in[9];
    const float* Wo      = (const float*)d_in[10];
    const float* bo      = (const float*)d_in[11];
    float* out = (float*)d_out;

    char* ws = (char*)d_ws;
    size_t off = 0;
    auto alloc = [&](size_t bytes) -> void* {
        void* p = ws + off;
        off = (off + bytes + 255) & ~(size_t)255;
        return p;
    };
    unsigned short* A2     = (unsigned short*)alloc((size_t)M_PAD * 256 * 2);
    unsigned short* B2qkv  = (unsigned short*)alloc((size_t)768 * 256 * 2);
    float*          biasC  = (float*)alloc(768 * sizeof(float));
    unsigned short* Qb     = (unsigned short*)alloc((size_t)N_NODES * HID * 2);
    unsigned short* Kb     = (unsigned short*)alloc((size_t)N_NODES * HID * 2);
    unsigned short* Vb     = (unsigned short*)alloc((size_t)N_NODES * HID * 2);
    unsigned short* accQ   = (unsigned short*)alloc((size_t)M_PAD * 512 * 2);
    unsigned short* B2o    = (unsigned short*)alloc((size_t)128 * 512 * 2);
    float* cntF = (float*)alloc((size_t)N_NODES * sizeof(float));
    int*   deg  = (int*)alloc((size_t)N_NODES * sizeof(int));
    int*   rowS = (int*)alloc((size_t)(N_NODES + 1) * sizeof(int));
    int*   curs = (int*)alloc((size_t)N_NODES * sizeof(int));
    int*   pck  = (int*)alloc((size_t)N_EDGES * sizeof(int));

    const dim3 blk(256);

    // pad rows -> zero (once per call; cheap, keeps garbage out of MFMA tails)
    hipMemsetAsync(A2 + (size_t)N_NODES * 256, 0, (size_t)(M_PAD - N_NODES) * 256 * 2, stream);
    hipMemsetAsync(accQ + (size_t)N_NODES * 512, 0, (size_t)(M_PAD - N_NODES) * 512 * 2, stream);

    // --- conversions + CSR build ---
    conv_nf_kernel<<<dim3((N_NODES * 32 + 255) / 256), blk, 0, stream>>>((const float4*)nf, A2);
    conv_w_kernel<<<dim3((768 * 128 + 255) / 256), blk, 0, stream>>>(Wq, Wk, Wv, bq, bk, bv, B2qkv, biasC);
    conv_wo_kernel<<<dim3((128 * 256 + 255) / 256), blk, 0, stream>>>(Wo, B2o);

    hipMemsetAsync(deg, 0, (size_t)N_NODES * sizeof(int), stream);
    hist_kernel<<<dim3((N_EDGES + 255) / 256), blk, 0, stream>>>(edges, deg);
    scan_kernel<<<dim3(1), dim3(1024), 0, stream>>>(deg, rowS, curs, cntF);
    scatter_kernel<<<dim3((N_EDGES + 255) / 256), blk, 0, stream>>>(edges, etypes, curs, pck);

    // --- fused QKV projection (MFMA): [M_PAD x 256] @ [768 x 256]^T ---
    mfma_gemm<0, 256, 768><<<dim3(6, M_PAD / 128), blk, 0, stream>>>(
        A2, B2qkv, biasC, nullptr, Qb, Kb, Vb, nullptr, N_NODES);

    // --- gather attention (wave per node, bf16 gathers, split-bf16 message out) ---
    node_gather_kernel<<<dim3((N_NODES + 3) / 4), blk, 0, stream>>>(
        pck, rowS, (const uint4*)Qb, (const uint4*)Kb, (const uint2*)Vb,
        (const float4*)ee, accQ);

    // --- output projection (MFMA): [M_PAD x 512] @ [128 x 512]^T + cnt*bo ---
    mfma_gemm<1, 512, 128><<<dim3(1, M_PAD / 128), blk, 0, stream>>>(
        accQ, B2o, bo, cntF, nullptr, nullptr, nullptr, out, N_NODES);
}

// Round 5
// 309.773 us; speedup vs baseline: 4.1527x; 1.4637x over previous
//
#include <hip/hip_runtime.h>

#define N_NODES 50000
#define N_EDGES 300000
#define M_PAD 50048   // 391 * 128

typedef __attribute__((ext_vector_type(8))) short bf16x8;
typedef __attribute__((ext_vector_type(4))) short bf16x4;
typedef __attribute__((ext_vector_type(4))) float f32x4;

__device__ __forceinline__ float bf2f(unsigned short h) { return __uint_as_float(((unsigned int)h) << 16); }
__device__ __forceinline__ unsigned short f2bf(float x) {
    unsigned int u = __float_as_uint(x);
    unsigned int r = (u + 0x7FFFu + ((u >> 16) & 1u)) >> 16;
    return (unsigned short)r;
}

typedef __attribute__((address_space(3))) unsigned int lds_uint;
typedef const __attribute__((address_space(1))) unsigned int glb_uint;
__device__ __forceinline__ void gld16(const void* g, void* l) {
    __builtin_amdgcn_global_load_lds((glb_uint*)g, (lds_uint*)l, 16, 0, 0);
}

// ---------------------------------------------------------------------------
// MFMA GEMM: C[M_PAD x NCOLS] = A2[M_PAD x 256](bf16) @ B2[NCOLS x 256](bf16)^T
// 128x128 tile, BK=64, 4 waves (2x2 of 64x64), 16x16x32 bf16 MFMA.
// MODE 0: NCOLS=768 -> Qb/Kb (row-major) + Vb (transposed [d][g]) + bias.
// MODE 1: NCOLS=128 -> fp32 out + cnt4-weighted eew/bo bias.
// ---------------------------------------------------------------------------
template <int MODE, int NCOLS>
__global__ __launch_bounds__(256)
void mfma_gemm(const unsigned short* __restrict__ A2, const unsigned short* __restrict__ B2,
               const float* __restrict__ biasCat,
               unsigned short* __restrict__ Qb, unsigned short* __restrict__ Kb,
               unsigned short* __restrict__ Vb,
               const float* __restrict__ eew, const float* __restrict__ bo,
               const float4* __restrict__ cnt4, float* __restrict__ Cout, int M)
{
    constexpr int K2 = 256;
    __shared__ unsigned short As[128 * 64];
    __shared__ unsigned short Bs[128 * 64];
    const int t = threadIdx.x;
    const int w = t >> 6;
    const int lane = t & 63;
    const int m0 = blockIdx.y * 128;
    const int n0 = blockIdx.x * 128;
    const int wm = (w >> 1) * 64;
    const int wn = (w & 1) * 64;

    f32x4 acc[4][4] = {};

    for (int kc = 0; kc < K2; kc += 64) {
        #pragma unroll
        for (int i = 0; i < 4; ++i) {
            const int chunk = i * 4 + w;
            const int o = (chunk * 64 + lane) * 16;
            const int row = o >> 7;
            const int cb = o & 127;
            const char* gA = (const char*)A2 + ((size_t)(m0 + row) * K2 + kc) * 2 + cb;
            const char* gB = (const char*)B2 + ((size_t)(n0 + row) * K2 + kc) * 2 + cb;
            gld16(gA, (char*)As + chunk * 1024);
            gld16(gB, (char*)Bs + chunk * 1024);
        }
        __syncthreads();

        bf16x8 af[4][2], bfr[4][2];
        #pragma unroll
        for (int mi = 0; mi < 4; ++mi)
            #pragma unroll
            for (int kk = 0; kk < 2; ++kk)
                af[mi][kk] = *(const bf16x8*)&As[(wm + mi * 16 + (lane & 15)) * 64 + kk * 32 + (lane >> 4) * 8];
        #pragma unroll
        for (int ni = 0; ni < 4; ++ni)
            #pragma unroll
            for (int kk = 0; kk < 2; ++kk)
                bfr[ni][kk] = *(const bf16x8*)&Bs[(wn + ni * 16 + (lane & 15)) * 64 + kk * 32 + (lane >> 4) * 8];

        #pragma unroll
        for (int mi = 0; mi < 4; ++mi)
            #pragma unroll
            for (int ni = 0; ni < 4; ++ni)
                #pragma unroll
                for (int kk = 0; kk < 2; ++kk)
                    acc[mi][ni] = __builtin_amdgcn_mfma_f32_16x16x32_bf16(
                        af[mi][kk], bfr[ni][kk], acc[mi][ni], 0, 0, 0);
        __syncthreads();
    }

    if (MODE == 0) {
        #pragma unroll
        for (int ni = 0; ni < 4; ++ni) {
            const int col = n0 + wn + ni * 16 + (lane & 15);
            const float bv_ = biasCat[col];
            const int c = col & 255;
            unsigned short* dst;
            size_t idxOff;
            if (col < 256)      { dst = Qb; idxOff = (size_t)c; }
            else if (col < 512) { dst = Kb; idxOff = (size_t)c; }
            else                { dst = Vb; idxOff = (size_t)((c & 31) * 8 + (c >> 5)); } // V^T [d][g]
            #pragma unroll
            for (int mi = 0; mi < 4; ++mi) {
                #pragma unroll
                for (int j = 0; j < 4; ++j) {
                    const int row = m0 + wm + mi * 16 + (lane >> 4) * 4 + j;
                    if (row < M) dst[(size_t)row * 256 + idxOff] = f2bf(acc[mi][ni][j] + bv_);
                }
            }
        }
    } else {
        #pragma unroll
        for (int mi = 0; mi < 4; ++mi) {
            #pragma unroll
            for (int j = 0; j < 4; ++j) {
                const int row = m0 + wm + mi * 16 + (lane >> 4) * 4 + j;
                if (row < M) {
                    const float4 cv = cnt4[row];
                    #pragma unroll
                    for (int ni = 0; ni < 4; ++ni) {
                        const int col = wn + ni * 16 + (lane & 15);
                        Cout[(size_t)row * NCOLS + col] = acc[mi][ni][j]
                            + cv.x * eew[col] + cv.y * eew[128 + col]
                            + cv.z * eew[256 + col] + cv.w * bo[col];
                    }
                }
            }
        }
    }
}

// ---------------------------------------------------------------------------
// Conversions / weight prep
// ---------------------------------------------------------------------------
__global__ __launch_bounds__(256)
void conv_nf_kernel(const float4* __restrict__ nf4, unsigned short* __restrict__ A2)
{
    const int tid = blockIdx.x * 256 + threadIdx.x;
    if (tid >= N_NODES * 32) return;
    const int m = tid >> 5, k4 = (tid & 31) * 4;
    const float4 v = nf4[tid];
    ushort4 hi, lo;
    hi.x = f2bf(v.x); lo.x = f2bf(v.x - bf2f(hi.x));
    hi.y = f2bf(v.y); lo.y = f2bf(v.y - bf2f(hi.y));
    hi.z = f2bf(v.z); lo.z = f2bf(v.z - bf2f(hi.z));
    hi.w = f2bf(v.w); lo.w = f2bf(v.w - bf2f(hi.w));
    *reinterpret_cast<ushort4*>(&A2[(size_t)m * 256 + k4]) = hi;
    *reinterpret_cast<ushort4*>(&A2[(size_t)m * 256 + 128 + k4]) = lo;
}

__global__ __launch_bounds__(256)
void prep_kernel(const float* __restrict__ Wq, const float* __restrict__ Wk,
                 const float* __restrict__ Wv, const float* __restrict__ bq,
                 const float* __restrict__ bk, const float* __restrict__ bv,
                 const float* __restrict__ Wo, const float* __restrict__ ee,
                 unsigned short* __restrict__ B2qkv, unsigned short* __restrict__ B2o,
                 float* __restrict__ biasCat, float* __restrict__ eew)
{
    const int bid = blockIdx.x, t = threadIdx.x;
    if (bid < 384) {
        const int tid = bid * 256 + t;          // 768*128
        const int r = tid >> 7, k = tid & 127;
        const float* W = (r < 256) ? Wq : (r < 512) ? Wk : Wv;
        const unsigned short h = f2bf(W[(size_t)(r & 255) * 128 + k]);
        B2qkv[(size_t)r * 256 + k] = h;
        B2qkv[(size_t)r * 256 + 128 + k] = h;
        if (k == 0) {
            const float* b = (r < 256) ? bq : (r < 512) ? bk : bv;
            biasCat[r] = b[r & 255];
        }
    } else if (bid < 512) {
        const int tid = (bid - 384) * 256 + t;  // 128*256
        const int r = tid >> 8, k = tid & 255;
        B2o[(size_t)r * 256 + k] = f2bf(Wo[(size_t)r * 256 + k]);
    } else if (t < 128) {
        float a0 = 0.f, a1 = 0.f, a2 = 0.f;
        for (int k = 0; k < 256; ++k) {
            const float w = Wo[(size_t)t * 256 + k];
            a0 += ee[k] * w; a1 += ee[256 + k] * w; a2 += ee[512 + k] * w;
        }
        eew[t] = a0; eew[128 + t] = a1; eew[256 + t] = a2;
    }
}

// ---------------------------------------------------------------------------
// CSR build
// ---------------------------------------------------------------------------
__global__ __launch_bounds__(256)
void hist_kernel(const int* __restrict__ edges, int* __restrict__ deg)
{
    const int e = blockIdx.x * 256 + threadIdx.x;
    if (e < N_EDGES) atomicAdd(&deg[edges[2 * e]], 1);
}

__global__ __launch_bounds__(1024)
void scan_kernel(const int* __restrict__ deg, int* __restrict__ rowStart,
                 int* __restrict__ cursor)
{
    __shared__ int lds[1024];
    const int t = threadIdx.x;
    const int CH = (N_NODES + 1023) / 1024;
    const int lo = t * CH;
    const int hi = min(lo + CH, N_NODES);
    int s = 0;
    for (int i = lo; i < hi; ++i) s += deg[i];
    lds[t] = s;
    __syncthreads();
    for (int offs = 1; offs < 1024; offs <<= 1) {
        const int v = (t >= offs) ? lds[t - offs] : 0;
        __syncthreads();
        lds[t] += v;
        __syncthreads();
    }
    int base = (t == 0) ? 0 : lds[t - 1];
    for (int i = lo; i < hi; ++i) {
        const int d = deg[i];
        rowStart[i] = base;
        cursor[i]   = base;
        base += d;
    }
    if (t == 1023) rowStart[N_NODES] = base;
}

__global__ __launch_bounds__(256)
void scatter_kernel(const int* __restrict__ edges, const int* __restrict__ etypes,
                    int* __restrict__ cursor, int* __restrict__ packed)
{
    const int e = blockIdx.x * 256 + threadIdx.x;
    if (e < N_EDGES) {
        const int pos = atomicAdd(&cursor[edges[2 * e]], 1);
        packed[pos] = edges[2 * e + 1] | (etypes[e] << 20);
    }
}

// ---------------------------------------------------------------------------
// MFMA gather attention: one wave per src node, 2 edges per iteration as a
// block-diagonal 16x16 problem.
//   score MFMA (16x16x32): A = K rows (m = 2x8 g), B = Q cols (n = 2x8 h),
//     D[g][h]; lane holds col h=lane&15, rows g=(lane>>4)*4+j.
//   softmax over g: in-lane over j + shfl_xor(16).
//   PV MFMA (16x16x16): A = block-diag P (the D-fragment maps in-lane to the
//     A-fragment!), B = V^T rows ([d][g] layout), accumulate C across edges.
// ---------------------------------------------------------------------------
__global__ __launch_bounds__(256)
void node_gather_kernel(const int* __restrict__ packed, const int* __restrict__ rowStart,
                        const unsigned short* __restrict__ Qb,
                        const unsigned short* __restrict__ Kb,
                        const unsigned short* __restrict__ Vb,
                        unsigned short* __restrict__ accQ, float4* __restrict__ cnt4)
{
    const int lane = threadIdx.x & 63;
    const int n = blockIdx.x * 4 + (threadIdx.x >> 6);
    if (n >= N_NODES) return;
    const int l15 = lane & 15;
    const int lg  = lane >> 4;

    // Q B-fragment: n-axis = h (same for both edge halves), k = d
    const bf16x8 qf = *(const bf16x8*)&Qb[(size_t)n * 256 + (l15 & 7) * 32 + lg * 8];

    f32x4 cpv0 = {0.f, 0.f, 0.f, 0.f};
    f32x4 cpv1 = {0.f, 0.f, 0.f, 0.f};
    int c0 = 0, c1 = 0, c2 = 0;

    const int lo = rowStart[n], hi = rowStart[n + 1];
    const bool validBase = ((l15 < 8) == (lg < 2));

    for (int idx = lo; idx < hi; idx += 2) {
        const int  p0  = packed[idx];
        const bool dup = (idx + 1 >= hi);
        const int  p1  = dup ? p0 : packed[idx + 1];
        const int  t0  = p0 & 0xFFFFF;
        const int  t1  = p1 & 0xFFFFF;
        const int  e0  = p0 >> 20;
        const int  e1  = p1 >> 20;
        c0 += (e0 == 0); c1 += (e0 == 1); c2 += (e0 == 2);
        if (!dup) { c0 += (e1 == 0); c1 += (e1 == 1); c2 += (e1 == 2); }

        // K A-fragment: m = l15 (rows 0-7 edge0 g, 8-15 edge1 g), k = d
        const int tk = (l15 < 8) ? t0 : t1;
        const bf16x8 kf = *(const bf16x8*)&Kb[(size_t)tk * 256 + (l15 & 7) * 32 + lg * 8];

        // V^T B-fragments: k = g-axis (0-7 edge0, 8-15 edge1), n = d half
        const int tv = (lg < 2) ? t0 : t1;
        const unsigned short* vrow = &Vb[(size_t)tv * 256 + (lg & 1) * 4];
        const bf16x4 vf0 = *(const bf16x4*)&vrow[l15 * 8];
        const bf16x4 vf1 = *(const bf16x4*)&vrow[(l15 + 16) * 8];

        // scores: D[g][h] = K @ Q^T
        f32x4 s = __builtin_amdgcn_mfma_f32_16x16x32_bf16(kf, qf, (f32x4){0.f, 0.f, 0.f, 0.f}, 0, 0, 0);
        const float SC = 0.17677669529663687f;
        const float s0 = s[0] * SC, s1 = s[1] * SC, s2 = s[2] * SC, s3 = s[3] * SC;

        float mx = fmaxf(fmaxf(s0, s1), fmaxf(s2, s3));
        mx = fmaxf(mx, __shfl_xor(mx, 16));
        const float ex0 = __expf(s0 - mx), ex1 = __expf(s1 - mx);
        const float ex2 = __expf(s2 - mx), ex3 = __expf(s3 - mx);
        float sum = ex0 + ex1 + ex2 + ex3;
        sum += __shfl_xor(sum, 16);
        const float inv = 1.0f / sum;

        // P -> bf16 A-fragment (in-lane!), zero off-diagonal / dup-edge1 blocks
        const bool valid = validBase && !(dup && (l15 >= 8));
        bf16x4 pa;
        pa[0] = valid ? (short)f2bf(ex0 * inv) : (short)0;
        pa[1] = valid ? (short)f2bf(ex1 * inv) : (short)0;
        pa[2] = valid ? (short)f2bf(ex2 * inv) : (short)0;
        pa[3] = valid ? (short)f2bf(ex3 * inv) : (short)0;

        cpv0 = __builtin_amdgcn_mfma_f32_16x16x16bf16_1k(pa, vf0, cpv0, 0, 0, 0);
        cpv1 = __builtin_amdgcn_mfma_f32_16x16x16bf16_1k(pa, vf1, cpv1, 0, 0, 0);
    }

    // fold edge0/edge1 h-blocks (rows m and m+8): groups 0,1 <- groups 2,3
    #pragma unroll
    for (int j = 0; j < 4; ++j) {
        cpv0[j] += __shfl_xor(cpv0[j], 32);
        cpv1[j] += __shfl_xor(cpv1[j], 32);
    }

    if (lane < 32) {
        unsigned short* row = &accQ[(size_t)n * 256];
        #pragma unroll
        for (int j = 0; j < 4; ++j) {
            const int h = lg * 4 + j;                    // lg in {0,1}
            row[h * 32 + l15]      = f2bf(cpv0[j]);
            row[h * 32 + 16 + l15] = f2bf(cpv1[j]);
        }
    }
    if (lane == 0)
        cnt4[n] = make_float4((float)c0, (float)c1, (float)c2, (float)(hi - lo));
}

// ---------------------------------------------------------------------------
extern "C" void kernel_launch(void* const* d_in, const int* in_sizes, int n_in,
                              void* d_out, int out_size, void* d_ws, size_t ws_size,
                              hipStream_t stream)
{
    const float* nf      = (const float*)d_in[0];
    const int*   edges   = (const int*)d_in[1];
    const int*   etypes  = (const int*)d_in[2];
    const float* Wq      = (const float*)d_in[3];
    const float* bq      = (const float*)d_in[4];
    const float* Wk      = (const float*)d_in[5];
    const float* bk      = (const float*)d_in[6];
    const float* Wv      = (const float*)d_in[7];
    const float* bv      = (const float*)d_in[8];
    const float* ee      = (const float*)d_in[9];
    const float* Wo      = (const float*)d_in[10];
    const float* bo      = (const float*)d_in[11];
    float* out = (float*)d_out;

    char* ws = (char*)d_ws;
    size_t off = 0;
    auto alloc = [&](size_t bytes) -> void* {
        void* p = ws + off;
        off = (off + bytes + 255) & ~(size_t)255;
        return p;
    };
    unsigned short* A2    = (unsigned short*)alloc((size_t)M_PAD * 256 * 2);
    unsigned short* B2qkv = (unsigned short*)alloc((size_t)768 * 256 * 2);
    unsigned short* B2o   = (unsigned short*)alloc((size_t)128 * 256 * 2);
    float*          biasC = (float*)alloc(768 * sizeof(float));
    float*          eew   = (float*)alloc(384 * sizeof(float));
    unsigned short* Qb    = (unsigned short*)alloc((size_t)N_NODES * 256 * 2);
    unsigned short* Kb    = (unsigned short*)alloc((size_t)N_NODES * 256 * 2);
    unsigned short* Vb    = (unsigned short*)alloc((size_t)N_NODES * 256 * 2);
    unsigned short* accQ  = (unsigned short*)alloc((size_t)M_PAD * 256 * 2);
    float4* cnt4 = (float4*)alloc((size_t)N_NODES * sizeof(float4));
    int*    deg  = (int*)alloc((size_t)N_NODES * sizeof(int));
    int*    rowS = (int*)alloc((size_t)(N_NODES + 1) * sizeof(int));
    int*    curs = (int*)alloc((size_t)N_NODES * sizeof(int));
    int*    pck  = (int*)alloc((size_t)N_EDGES * sizeof(int));

    const dim3 blk(256);

    // conversions + weight prep
    conv_nf_kernel<<<dim3((N_NODES * 32 + 255) / 256), blk, 0, stream>>>((const float4*)nf, A2);
    prep_kernel<<<dim3(513), blk, 0, stream>>>(Wq, Wk, Wv, bq, bk, bv, Wo, ee, B2qkv, B2o, biasC, eew);

    // CSR build
    hipMemsetAsync(deg, 0, (size_t)N_NODES * sizeof(int), stream);
    hist_kernel<<<dim3((N_EDGES + 255) / 256), blk, 0, stream>>>(edges, deg);
    scan_kernel<<<dim3(1), dim3(1024), 0, stream>>>(deg, rowS, curs);
    scatter_kernel<<<dim3((N_EDGES + 255) / 256), blk, 0, stream>>>(edges, etypes, curs, pck);

    // fused QKV projection (MFMA): [M_PAD x 256] @ [768 x 256]^T
    mfma_gemm<0, 768><<<dim3(6, M_PAD / 128), blk, 0, stream>>>(
        A2, B2qkv, biasC, Qb, Kb, Vb, nullptr, nullptr, nullptr, nullptr, N_NODES);

    // MFMA gather attention
    node_gather_kernel<<<dim3((N_NODES + 3) / 4), blk, 0, stream>>>(
        pck, rowS, Qb, Kb, Vb, accQ, cnt4);

    // output projection (MFMA): [M_PAD x 256] @ [128 x 256]^T + cnt-weighted bias
    mfma_gemm<1, 128><<<dim3(1, M_PAD / 128), blk, 0, stream>>>(
        accQ, B2o, nullptr, nullptr, nullptr, nullptr, eew, bo, cnt4, out, N_NODES);
}

// Round 6
// 211.871 us; speedup vs baseline: 6.0717x; 1.4621x over previous
//
#include <hip/hip_runtime.h>

#define N_NODES 50000
#define N_EDGES 300000
#define M_PAD 50048   // 391 * 128
#define NBLK 196      // ceil(N_NODES/256)

typedef __attribute__((ext_vector_type(8))) short bf16x8;
typedef __attribute__((ext_vector_type(4))) short bf16x4;
typedef __attribute__((ext_vector_type(4))) float f32x4;

__device__ __forceinline__ float bf2f(unsigned short h) { return __uint_as_float(((unsigned int)h) << 16); }
__device__ __forceinline__ unsigned short f2bf(float x) {
    unsigned int u = __float_as_uint(x);
    unsigned int r = (u + 0x7FFFu + ((u >> 16) & 1u)) >> 16;
    return (unsigned short)r;
}

typedef __attribute__((address_space(3))) unsigned int lds_uint;
typedef const __attribute__((address_space(1))) unsigned int glb_uint;
__device__ __forceinline__ void gld16(const void* g, void* l) {
    __builtin_amdgcn_global_load_lds((glb_uint*)g, (lds_uint*)l, 16, 0, 0);
}

// ---------------------------------------------------------------------------
// MFMA GEMM: C[M_PAD x NCOLS] = A2[M_PAD x 256](bf16) @ B2[NCOLS x 256](bf16)^T
// 128x128 tile, BK=64, 4 waves (2x2 of 64x64), 16x16x32 bf16 MFMA.
// MODE 0: NCOLS=768 -> Qb/Kb (row-major) + Vb (transposed [d][g]) + bias.
// MODE 1: NCOLS=128 -> fp32 out + cnt4-weighted eew/bo bias.
// ---------------------------------------------------------------------------
template <int MODE, int NCOLS>
__global__ __launch_bounds__(256)
void mfma_gemm(const unsigned short* __restrict__ A2, const unsigned short* __restrict__ B2,
               const float* __restrict__ biasCat,
               unsigned short* __restrict__ Qb, unsigned short* __restrict__ Kb,
               unsigned short* __restrict__ Vb,
               const float* __restrict__ eew, const float* __restrict__ bo,
               const float4* __restrict__ cnt4, float* __restrict__ Cout, int M)
{
    constexpr int K2 = 256;
    __shared__ unsigned short As[128 * 64];
    __shared__ unsigned short Bs[128 * 64];
    const int t = threadIdx.x;
    const int w = t >> 6;
    const int lane = t & 63;
    const int m0 = blockIdx.y * 128;
    const int n0 = blockIdx.x * 128;
    const int wm = (w >> 1) * 64;
    const int wn = (w & 1) * 64;

    f32x4 acc[4][4] = {};

    for (int kc = 0; kc < K2; kc += 64) {
        #pragma unroll
        for (int i = 0; i < 4; ++i) {
            const int chunk = i * 4 + w;
            const int o = (chunk * 64 + lane) * 16;
            const int row = o >> 7;
            const int cb = o & 127;
            const char* gA = (const char*)A2 + ((size_t)(m0 + row) * K2 + kc) * 2 + cb;
            const char* gB = (const char*)B2 + ((size_t)(n0 + row) * K2 + kc) * 2 + cb;
            gld16(gA, (char*)As + chunk * 1024);
            gld16(gB, (char*)Bs + chunk * 1024);
        }
        __syncthreads();

        bf16x8 af[4][2], bfr[4][2];
        #pragma unroll
        for (int mi = 0; mi < 4; ++mi)
            #pragma unroll
            for (int kk = 0; kk < 2; ++kk)
                af[mi][kk] = *(const bf16x8*)&As[(wm + mi * 16 + (lane & 15)) * 64 + kk * 32 + (lane >> 4) * 8];
        #pragma unroll
        for (int ni = 0; ni < 4; ++ni)
            #pragma unroll
            for (int kk = 0; kk < 2; ++kk)
                bfr[ni][kk] = *(const bf16x8*)&Bs[(wn + ni * 16 + (lane & 15)) * 64 + kk * 32 + (lane >> 4) * 8];

        #pragma unroll
        for (int mi = 0; mi < 4; ++mi)
            #pragma unroll
            for (int ni = 0; ni < 4; ++ni)
                #pragma unroll
                for (int kk = 0; kk < 2; ++kk)
                    acc[mi][ni] = __builtin_amdgcn_mfma_f32_16x16x32_bf16(
                        af[mi][kk], bfr[ni][kk], acc[mi][ni], 0, 0, 0);
        __syncthreads();
    }

    if (MODE == 0) {
        #pragma unroll
        for (int ni = 0; ni < 4; ++ni) {
            const int col = n0 + wn + ni * 16 + (lane & 15);
            const float bv_ = biasCat[col];
            const int c = col & 255;
            unsigned short* dst;
            size_t idxOff;
            if (col < 256)      { dst = Qb; idxOff = (size_t)c; }
            else if (col < 512) { dst = Kb; idxOff = (size_t)c; }
            else                { dst = Vb; idxOff = (size_t)((c & 31) * 8 + (c >> 5)); } // V^T [d][g]
            #pragma unroll
            for (int mi = 0; mi < 4; ++mi) {
                #pragma unroll
                for (int j = 0; j < 4; ++j) {
                    const int row = m0 + wm + mi * 16 + (lane >> 4) * 4 + j;
                    if (row < M) dst[(size_t)row * 256 + idxOff] = f2bf(acc[mi][ni][j] + bv_);
                }
            }
        }
    } else {
        #pragma unroll
        for (int mi = 0; mi < 4; ++mi) {
            #pragma unroll
            for (int j = 0; j < 4; ++j) {
                const int row = m0 + wm + mi * 16 + (lane >> 4) * 4 + j;
                if (row < M) {
                    const float4 cv = cnt4[row];
                    #pragma unroll
                    for (int ni = 0; ni < 4; ++ni) {
                        const int col = wn + ni * 16 + (lane & 15);
                        Cout[(size_t)row * NCOLS + col] = acc[mi][ni][j]
                            + cv.x * eew[col] + cv.y * eew[128 + col]
                            + cv.z * eew[256 + col] + cv.w * bo[col];
                    }
                }
            }
        }
    }
}

// ---------------------------------------------------------------------------
// Conversions / weight prep
// ---------------------------------------------------------------------------
__global__ __launch_bounds__(256)
void conv_nf_kernel(const float4* __restrict__ nf4, unsigned short* __restrict__ A2)
{
    const int tid = blockIdx.x * 256 + threadIdx.x;
    if (tid >= N_NODES * 32) return;
    const int m = tid >> 5, k4 = (tid & 31) * 4;
    const float4 v = nf4[tid];
    ushort4 hi, lo;
    hi.x = f2bf(v.x); lo.x = f2bf(v.x - bf2f(hi.x));
    hi.y = f2bf(v.y); lo.y = f2bf(v.y - bf2f(hi.y));
    hi.z = f2bf(v.z); lo.z = f2bf(v.z - bf2f(hi.z));
    hi.w = f2bf(v.w); lo.w = f2bf(v.w - bf2f(hi.w));
    *reinterpret_cast<ushort4*>(&A2[(size_t)m * 256 + k4]) = hi;
    *reinterpret_cast<ushort4*>(&A2[(size_t)m * 256 + 128 + k4]) = lo;
}

__global__ __launch_bounds__(256)
void prep_kernel(const float* __restrict__ Wq, const float* __restrict__ Wk,
                 const float* __restrict__ Wv, const float* __restrict__ bq,
                 const float* __restrict__ bk, const float* __restrict__ bv,
                 const float* __restrict__ Wo, const float* __restrict__ ee,
                 unsigned short* __restrict__ B2qkv, unsigned short* __restrict__ B2o,
                 float* __restrict__ biasCat, float* __restrict__ eew)
{
    const int bid = blockIdx.x, t = threadIdx.x;
    if (bid < 384) {
        const int tid = bid * 256 + t;          // 768*128
        const int r = tid >> 7, k = tid & 127;
        const float* W = (r < 256) ? Wq : (r < 512) ? Wk : Wv;
        const unsigned short h = f2bf(W[(size_t)(r & 255) * 128 + k]);
        B2qkv[(size_t)r * 256 + k] = h;
        B2qkv[(size_t)r * 256 + 128 + k] = h;
        if (k == 0) {
            const float* b = (r < 256) ? bq : (r < 512) ? bk : bv;
            biasCat[r] = b[r & 255];
        }
    } else if (bid < 512) {
        const int tid = (bid - 384) * 256 + t;  // 128*256
        const int r = tid >> 8, k = tid & 255;
        B2o[(size_t)r * 256 + k] = f2bf(Wo[(size_t)r * 256 + k]);
    } else if (t < 128) {
        float a0 = 0.f, a1 = 0.f, a2 = 0.f;
        for (int k = 0; k < 256; ++k) {
            const float w = Wo[(size_t)t * 256 + k];
            a0 += ee[k] * w; a1 += ee[256 + k] * w; a2 += ee[512 + k] * w;
        }
        eew[t] = a0; eew[128 + t] = a1; eew[256 + t] = a2;
    }
}

// ---------------------------------------------------------------------------
// CSR build: hist -> hierarchical scan (3 small parallel kernels) -> scatter
// ---------------------------------------------------------------------------
__global__ __launch_bounds__(256)
void hist_kernel(const int* __restrict__ edges, int* __restrict__ deg)
{
    const int e = blockIdx.x * 256 + threadIdx.x;
    if (e < N_EDGES) atomicAdd(&deg[edges[2 * e]], 1);
}

__global__ __launch_bounds__(256)
void scan_part1(const int* __restrict__ deg, int* __restrict__ blockSum)
{
    const int t = threadIdx.x;
    const int i = blockIdx.x * 256 + t;
    int v = (i < N_NODES) ? deg[i] : 0;
    #pragma unroll
    for (int o = 1; o < 64; o <<= 1) v += __shfl_xor(v, o);
    __shared__ int ws[4];
    if ((t & 63) == 0) ws[t >> 6] = v;
    __syncthreads();
    if (t == 0) blockSum[blockIdx.x] = ws[0] + ws[1] + ws[2] + ws[3];
}

__global__ __launch_bounds__(256)
void scan_part2(const int* __restrict__ blockSum, int* __restrict__ blockBase,
                int* __restrict__ rowStart)
{
    __shared__ int lds[256];
    const int t = threadIdx.x;
    lds[t] = (t < NBLK) ? blockSum[t] : 0;
    __syncthreads();
    #pragma unroll
    for (int o = 1; o < 256; o <<= 1) {
        const int u = (t >= o) ? lds[t - o] : 0;
        __syncthreads();
        lds[t] += u;
        __syncthreads();
    }
    if (t < NBLK) blockBase[t] = (t == 0) ? 0 : lds[t - 1];
    if (t == 0) rowStart[N_NODES] = N_EDGES;   // total is a constant
}

__global__ __launch_bounds__(256)
void scan_part3(const int* __restrict__ deg, const int* __restrict__ blockBase,
                int* __restrict__ rowStart, int* __restrict__ cursor)
{
    const int t = threadIdx.x;
    const int lane = t & 63, wid = t >> 6;
    const int i = blockIdx.x * 256 + t;
    const int d = (i < N_NODES) ? deg[i] : 0;
    int x = d;
    #pragma unroll
    for (int o = 1; o < 64; o <<= 1) {
        const int u = __shfl_up(x, o);
        if (lane >= o) x += u;
    }
    __shared__ int wtot[4];
    if (lane == 63) wtot[wid] = x;
    __syncthreads();
    int wo = 0;
    #pragma unroll
    for (int wi = 0; wi < 3; ++wi) wo += (wi < wid) ? wtot[wi] : 0;
    const int excl = blockBase[blockIdx.x] + wo + x - d;
    if (i < N_NODES) { rowStart[i] = excl; cursor[i] = excl; }
}

__global__ __launch_bounds__(256)
void scatter_kernel(const int* __restrict__ edges, const int* __restrict__ etypes,
                    int* __restrict__ cursor, int* __restrict__ packed)
{
    const int e = blockIdx.x * 256 + threadIdx.x;
    if (e < N_EDGES) {
        const int pos = atomicAdd(&cursor[edges[2 * e]], 1);
        packed[pos] = edges[2 * e + 1] | (etypes[e] << 20);
    }
}

// ---------------------------------------------------------------------------
// MFMA gather attention: one wave per src node, 2 edges per iteration as a
// block-diagonal 16x16 problem.
// ---------------------------------------------------------------------------
__global__ __launch_bounds__(256)
void node_gather_kernel(const int* __restrict__ packed, const int* __restrict__ rowStart,
                        const unsigned short* __restrict__ Qb,
                        const unsigned short* __restrict__ Kb,
                        const unsigned short* __restrict__ Vb,
                        unsigned short* __restrict__ accQ, float4* __restrict__ cnt4)
{
    const int lane = threadIdx.x & 63;
    const int n = blockIdx.x * 4 + (threadIdx.x >> 6);
    if (n >= N_NODES) return;
    const int l15 = lane & 15;
    const int lg  = lane >> 4;

    const bf16x8 qf = *(const bf16x8*)&Qb[(size_t)n * 256 + (l15 & 7) * 32 + lg * 8];

    f32x4 cpv0 = {0.f, 0.f, 0.f, 0.f};
    f32x4 cpv1 = {0.f, 0.f, 0.f, 0.f};
    int c0 = 0, c1 = 0, c2 = 0;

    const int lo = rowStart[n], hi = rowStart[n + 1];
    const bool validBase = ((l15 < 8) == (lg < 2));

    for (int idx = lo; idx < hi; idx += 2) {
        const int  p0  = packed[idx];
        const bool dup = (idx + 1 >= hi);
        const int  p1  = dup ? p0 : packed[idx + 1];
        const int  t0  = p0 & 0xFFFFF;
        const int  t1  = p1 & 0xFFFFF;
        const int  e0  = p0 >> 20;
        const int  e1  = p1 >> 20;
        c0 += (e0 == 0); c1 += (e0 == 1); c2 += (e0 == 2);
        if (!dup) { c0 += (e1 == 0); c1 += (e1 == 1); c2 += (e1 == 2); }

        const int tk = (l15 < 8) ? t0 : t1;
        const bf16x8 kf = *(const bf16x8*)&Kb[(size_t)tk * 256 + (l15 & 7) * 32 + lg * 8];

        const int tv = (lg < 2) ? t0 : t1;
        const unsigned short* vrow = &Vb[(size_t)tv * 256 + (lg & 1) * 4];
        const bf16x4 vf0 = *(const bf16x4*)&vrow[l15 * 8];
        const bf16x4 vf1 = *(const bf16x4*)&vrow[(l15 + 16) * 8];

        f32x4 s = __builtin_amdgcn_mfma_f32_16x16x32_bf16(kf, qf, (f32x4){0.f, 0.f, 0.f, 0.f}, 0, 0, 0);
        const float SC = 0.17677669529663687f;
        const float s0 = s[0] * SC, s1 = s[1] * SC, s2 = s[2] * SC, s3 = s[3] * SC;

        float mx = fmaxf(fmaxf(s0, s1), fmaxf(s2, s3));
        mx = fmaxf(mx, __shfl_xor(mx, 16));
        const float ex0 = __expf(s0 - mx), ex1 = __expf(s1 - mx);
        const float ex2 = __expf(s2 - mx), ex3 = __expf(s3 - mx);
        float sum = ex0 + ex1 + ex2 + ex3;
        sum += __shfl_xor(sum, 16);
        const float inv = 1.0f / sum;

        const bool valid = validBase && !(dup && (l15 >= 8));
        bf16x4 pa;
        pa[0] = valid ? (short)f2bf(ex0 * inv) : (short)0;
        pa[1] = valid ? (short)f2bf(ex1 * inv) : (short)0;
        pa[2] = valid ? (short)f2bf(ex2 * inv) : (short)0;
        pa[3] = valid ? (short)f2bf(ex3 * inv) : (short)0;

        cpv0 = __builtin_amdgcn_mfma_f32_16x16x16bf16_1k(pa, vf0, cpv0, 0, 0, 0);
        cpv1 = __builtin_amdgcn_mfma_f32_16x16x16bf16_1k(pa, vf1, cpv1, 0, 0, 0);
    }

    #pragma unroll
    for (int j = 0; j < 4; ++j) {
        cpv0[j] += __shfl_xor(cpv0[j], 32);
        cpv1[j] += __shfl_xor(cpv1[j], 32);
    }

    if (lane < 32) {
        unsigned short* row = &accQ[(size_t)n * 256];
        #pragma unroll
        for (int j = 0; j < 4; ++j) {
            const int h = lg * 4 + j;
            row[h * 32 + l15]      = f2bf(cpv0[j]);
            row[h * 32 + 16 + l15] = f2bf(cpv1[j]);
        }
    }
    if (lane == 0)
        cnt4[n] = make_float4((float)c0, (float)c1, (float)c2, (float)(hi - lo));
}

// ---------------------------------------------------------------------------
extern "C" void kernel_launch(void* const* d_in, const int* in_sizes, int n_in,
                              void* d_out, int out_size, void* d_ws, size_t ws_size,
                              hipStream_t stream)
{
    const float* nf      = (const float*)d_in[0];
    const int*   edges   = (const int*)d_in[1];
    const int*   etypes  = (const int*)d_in[2];
    const float* Wq      = (const float*)d_in[3];
    const float* bq      = (const float*)d_in[4];
    const float* Wk      = (const float*)d_in[5];
    const float* bk      = (const float*)d_in[6];
    const float* Wv      = (const float*)d_in[7];
    const float* bv      = (const float*)d_in[8];
    const float* ee      = (const float*)d_in[9];
    const float* Wo      = (const float*)d_in[10];
    const float* bo      = (const float*)d_in[11];
    float* out = (float*)d_out;

    char* ws = (char*)d_ws;
    size_t off = 0;
    auto alloc = [&](size_t bytes) -> void* {
        void* p = ws + off;
        off = (off + bytes + 255) & ~(size_t)255;
        return p;
    };
    unsigned short* A2    = (unsigned short*)alloc((size_t)M_PAD * 256 * 2);
    unsigned short* B2qkv = (unsigned short*)alloc((size_t)768 * 256 * 2);
    unsigned short* B2o   = (unsigned short*)alloc((size_t)128 * 256 * 2);
    float*          biasC = (float*)alloc(768 * sizeof(float));
    float*          eew   = (float*)alloc(384 * sizeof(float));
    unsigned short* Qb    = (unsigned short*)alloc((size_t)N_NODES * 256 * 2);
    unsigned short* Kb    = (unsigned short*)alloc((size_t)N_NODES * 256 * 2);
    unsigned short* Vb    = (unsigned short*)alloc((size_t)N_NODES * 256 * 2);
    unsigned short* accQ  = (unsigned short*)alloc((size_t)M_PAD * 256 * 2);
    float4* cnt4 = (float4*)alloc((size_t)N_NODES * sizeof(float4));
    int*    deg  = (int*)alloc((size_t)N_NODES * sizeof(int));
    int*    rowS = (int*)alloc((size_t)(N_NODES + 1) * sizeof(int));
    int*    curs = (int*)alloc((size_t)N_NODES * sizeof(int));
    int*    pck  = (int*)alloc((size_t)N_EDGES * sizeof(int));
    int*    bSum = (int*)alloc((size_t)NBLK * sizeof(int));
    int*    bBase= (int*)alloc((size_t)NBLK * sizeof(int));

    const dim3 blk(256);

    // conversions + weight prep
    conv_nf_kernel<<<dim3((N_NODES * 32 + 255) / 256), blk, 0, stream>>>((const float4*)nf, A2);
    prep_kernel<<<dim3(513), blk, 0, stream>>>(Wq, Wk, Wv, bq, bk, bv, Wo, ee, B2qkv, B2o, biasC, eew);

    // CSR build (hierarchical scan)
    hipMemsetAsync(deg, 0, (size_t)N_NODES * sizeof(int), stream);
    hist_kernel<<<dim3((N_EDGES + 255) / 256), blk, 0, stream>>>(edges, deg);
    scan_part1<<<dim3(NBLK), blk, 0, stream>>>(deg, bSum);
    scan_part2<<<dim3(1), blk, 0, stream>>>(bSum, bBase, rowS);
    scan_part3<<<dim3(NBLK), blk, 0, stream>>>(deg, bBase, rowS, curs);
    scatter_kernel<<<dim3((N_EDGES + 255) / 256), blk, 0, stream>>>(edges, etypes, curs, pck);

    // fused QKV projection (MFMA): [M_PAD x 256] @ [768 x 256]^T
    mfma_gemm<0, 768><<<dim3(6, M_PAD / 128), blk, 0, stream>>>(
        A2, B2qkv, biasC, Qb, Kb, Vb, nullptr, nullptr, nullptr, nullptr, N_NODES);

    // MFMA gather attention
    node_gather_kernel<<<dim3((N_NODES + 3) / 4), blk, 0, stream>>>(
        pck, rowS, Qb, Kb, Vb, accQ, cnt4);

    // output projection (MFMA): [M_PAD x 256] @ [128 x 256]^T + cnt-weighted bias
    mfma_gemm<1, 128><<<dim3(1, M_PAD / 128), blk, 0, stream>>>(
        accQ, B2o, nullptr, nullptr, nullptr, nullptr, eew, bo, cnt4, out, N_NODES);
}